// Round 5
// baseline (170.021 us; speedup 1.0000x reference)
//
#include <hip/hip_runtime.h>

#define TSEQ 2048
#define NHEAD 16
#define DHEAD 64
#define CDIM 1024
#define BATCH 2

typedef __attribute__((ext_vector_type(8))) short bfx8;
typedef __attribute__((ext_vector_type(4))) short bfx4;
typedef __attribute__((ext_vector_type(4))) float f32x4;

__device__ __forceinline__ unsigned short f2bf(float f) {
  unsigned u = __builtin_bit_cast(unsigned, f);
  u += 0x7fffu + ((u >> 16) & 1u);
  return (unsigned short)(u >> 16);
}

__device__ __forceinline__ unsigned cvtpk(float lo, float hi) {
  unsigned r;
  asm("v_cvt_pk_bf16_f32 %0, %1, %2" : "=v"(r) : "v"(lo), "v"(hi));
  return r;
}

__device__ __forceinline__ void gload16(const void* g, void* l) {
  __builtin_amdgcn_global_load_lds(
      (const __attribute__((address_space(1))) unsigned*)g,
      (__attribute__((address_space(3))) unsigned*)l, 16, 0, 0);
}

// ---------------- elementwise fp32 -> bf16 conversion (x + 4 weights) -------
__global__ __launch_bounds__(256) void convert_all(
    const float* __restrict__ x,
    const float* __restrict__ wq, const float* __restrict__ wk,
    const float* __restrict__ wv, const float* __restrict__ wo,
    short* __restrict__ xb, short* __restrict__ wall) {
  const int y = blockIdx.y;
  const float* src;
  short* dst;
  int n;
  if (y == 0) { src = x; dst = xb; n = (BATCH * TSEQ * CDIM) / 4; }
  else {
    src = (y == 1) ? wq : (y == 2) ? wk : (y == 3) ? wv : wo;
    dst = wall + (size_t)(y - 1) * CDIM * CDIM;
    n = (CDIM * CDIM) / 4;
  }
  const int i = blockIdx.x * 256 + threadIdx.x;
  if (i < n) {
    const float4 v = ((const float4*)src)[i];
    bfx4 o;
    o[0] = (short)f2bf(v.x); o[1] = (short)f2bf(v.y);
    o[2] = (short)f2bf(v.z); o[3] = (short)f2bf(v.w);
    ((bfx4*)dst)[i] = o;
  }
}

// ---------------- combined mask pre-pack ------------------------------------
// pm ushort layout: idx = ((b*T + q)*32 + tile)*4 + g ; bit (blk*4+r) set =>
// (q, k=tile*64+blk*16+g*4+r) is MASKED (causal | dynamic). 1 MB total ->
// L2-resident in attn; one u16 load per lane per tile-phase.
__global__ __launch_bounds__(256) void maskpack(
    const unsigned char* __restrict__ dyn,
    const unsigned char* __restrict__ causal,
    unsigned long long* __restrict__ pm) {
  const bool mbyte = (causal[32] != 0);  // dyn dtype probe (bool-as-byte?)
  const int gid = blockIdx.x * 256 + threadIdx.x;  // (b*T + q)*32 + tile
  const int tile = gid & 31;
  const int q = (gid >> 5) & (TSEQ - 1);
  const int b = gid >> 16;
  const int k0 = tile * 64;
  const bool qok = (q & 3) != 3;
  const int qch = q >> 5;
  const unsigned char* d8 = dyn + ((size_t)b * TSEQ + q) * TSEQ + k0;
  const int* d32 = (const int*)dyn + ((size_t)b * TSEQ + q) * TSEQ + k0;
  unsigned long long out = 0;
#pragma unroll
  for (int g = 0; g < 4; ++g)
#pragma unroll
    for (int blk = 0; blk < 4; ++blk)
#pragma unroll
      for (int r = 0; r < 4; ++r) {
        const int kl = blk * 16 + g * 4 + r;
        const int k = k0 + kl;
        const bool dm = mbyte ? (d8[kl] != 0) : (d32[kl] != 0);
        const bool al =
            (((k >> 5) == qch) || ((k <= q) && qok && ((k & 3) != 3))) && !dm;
        if (!al) out |= 1ull << (g * 16 + blk * 4 + r);
      }
  pm[gid] = out;
}

// ---------------- NT GEMM (A[M][K] bf16, B[N][K] bf16), 128x128 tile --------
template <int MODE>
__global__ __launch_bounds__(256) void gemm_nt(
    const short* __restrict__ A, const short* __restrict__ Ball,
    const float* __restrict__ bias0, const float* __restrict__ bias1,
    const float* __restrict__ bias2,
    short* __restrict__ Oq, short* __restrict__ Ok, short* __restrict__ Ov,
    float* __restrict__ Of) {
  __shared__ short As[128 * 32];
  __shared__ short Bs[128 * 32];
  const int tid = threadIdx.x;
  const int w = tid >> 6, lane = tid & 63;
  const int lq = lane & 15, g = lane >> 4;
  const int wr = w >> 1, wc = w & 1;
  const int m0 = blockIdx.x * 128, n0 = blockIdx.y * 128;
  const int which = (MODE == 0) ? (int)blockIdx.z : 3;
  const short* B = Ball + (size_t)which * CDIM * CDIM;
  f32x4 acc[4][4] = {};
  for (int kt = 0; kt < CDIM / 32; ++kt) {
#pragma unroll
    for (int ph = 0; ph < 2; ++ph) {
      const int c = ph * 256 + tid;  // chunk: row=c>>2, k-part=(c&3)*8
      gload16(A + (size_t)(m0 + (c >> 2)) * CDIM + kt * 32 + (c & 3) * 8,
              As + (size_t)(ph * 256 + w * 64) * 8);
      gload16(B + (size_t)(n0 + (c >> 2)) * CDIM + kt * 32 + (c & 3) * 8,
              Bs + (size_t)(ph * 256 + w * 64) * 8);
    }
    __syncthreads();
    bfx8 af[4], bfr[4];
#pragma unroll
    for (int i = 0; i < 4; ++i)
      af[i] = *(const bfx8*)&As[(wr * 64 + i * 16 + lq) * 32 + g * 8];
#pragma unroll
    for (int i = 0; i < 4; ++i)
      bfr[i] = *(const bfx8*)&Bs[(wc * 64 + i * 16 + lq) * 32 + g * 8];
#pragma unroll
    for (int i = 0; i < 4; ++i)
#pragma unroll
      for (int j = 0; j < 4; ++j)
        acc[i][j] = __builtin_amdgcn_mfma_f32_16x16x32_bf16(af[i], bfr[j],
                                                            acc[i][j], 0, 0, 0);
    __syncthreads();
  }
  if (MODE == 0) {
    const float* bias = (which == 0) ? bias0 : (which == 1) ? bias1 : bias2;
    const float scale = (which == 0) ? 0.18033688011112042f : 1.0f;
    short* O = (which == 0) ? Oq : (which == 1) ? Ok : Ov;
#pragma unroll
    for (int i = 0; i < 4; ++i)
#pragma unroll
      for (int j = 0; j < 4; ++j) {
        const int col = n0 + wc * 64 + j * 16 + lq;  // c = h*64+d
        const int h = col >> 6, d = col & 63;
        const float bb = bias[col];
#pragma unroll
        for (int r = 0; r < 4; ++r) {
          const int row = m0 + wr * 64 + i * 16 + g * 4 + r;  // b*T+t
          const int b_ = row >> 11, t = row & (TSEQ - 1);
          O[(((size_t)b_ * NHEAD + h) * TSEQ + t) * DHEAD + d] =
              (short)f2bf((acc[i][j][r] + bb) * scale);
        }
      }
  } else {
    const float* bias = bias0;
#pragma unroll
    for (int i = 0; i < 4; ++i)
#pragma unroll
      for (int j = 0; j < 4; ++j) {
        const int col = n0 + wc * 64 + j * 16 + lq;
        const float bb = bias[col];
#pragma unroll
        for (int r = 0; r < 4; ++r) {
          const int row = m0 + wr * 64 + i * 16 + g * 4 + r;
          Of[(size_t)row * CDIM + col] = acc[i][j][r] + bb;
        }
      }
  }
}

// ---------------- V (b,h,t,d) -> VT (b,h,d,t) -------------------------------
__global__ __launch_bounds__(256) void vtrans(const short* __restrict__ V,
                                              short* __restrict__ VT) {
  __shared__ short tile[64][72];
  const int bh = blockIdx.y;
  const int t0 = blockIdx.x * 64;
  const int tid = threadIdx.x;
  const short* src = V + ((size_t)bh * TSEQ + t0) * DHEAD;
#pragma unroll
  for (int ph = 0; ph < 4; ++ph) {
    const int c = ph * 256 + tid;
    const int row = c >> 4, col = (c & 15) * 4;
    *(bfx4*)&tile[row][col] = *(const bfx4*)(src + row * DHEAD + col);
  }
  __syncthreads();
  short* dst = VT + (size_t)bh * DHEAD * TSEQ + t0;
#pragma unroll
  for (int ph = 0; ph < 4; ++ph) {
    const int c = ph * 256 + tid;
    const int d = c >> 4, tc = (c & 15) * 4;
    bfx4 o;
    o[0] = tile[tc][d]; o[1] = tile[tc + 1][d];
    o[2] = tile[tc + 2][d]; o[3] = tile[tc + 3][d];
    *(bfx4*)(dst + (size_t)d * TSEQ + tc) = o;
  }
}

// ---------------- fused flash attention v4 ----------------------------------
// v3 + (a) pre-packed combined mask (one u16 load per tile-phase, no causal
// math, no dyn int4 loads), (b) defer-max (T13, THR=8): fast path has ZERO
// cross-lane ops -- no max/sum shuffle reduces, no rescale; l accumulates
// per-lane and is reduced once at the end. Deferred factor cancels in acc/l.
struct QPhase {
  bfx8 qf0, qf1;
  f32x4 acc[4];
  float m, l;
  const unsigned short* pmr;  // packed-mask base for (b,q,g)
};

__device__ __forceinline__ void attn_tile(QPhase& S, const char* kbuf,
                                          const char* vbuf, short* Pw,
                                          int t, int sw, int lq, int g) {
  const unsigned mbits = S.pmr[t << 2];  // bit idx set => masked
  // QK^T (S^T quadrants)
  f32x4 st[4] = {};
#pragma unroll
  for (int blk = 0; blk < 4; ++blk) {
    const int rowb = (blk * 16 + lq) * 128;
    const bfx8 kf0 = *(const bfx8*)&kbuf[rowb + ((g * 16) ^ sw)];
    const bfx8 kf1 = *(const bfx8*)&kbuf[rowb + ((64 + g * 16) ^ sw)];
    st[blk] =
        __builtin_amdgcn_mfma_f32_16x16x32_bf16(kf0, S.qf0, st[blk], 0, 0, 0);
    st[blk] =
        __builtin_amdgcn_mfma_f32_16x16x32_bf16(kf1, S.qf1, st[blk], 0, 0, 0);
  }
  float s16[16];
  float pmax = -3.0e38f;
#pragma unroll
  for (int idx = 0; idx < 16; ++idx) {
    const float s = ((mbits >> idx) & 1u) ? -3.0e38f : st[idx >> 2][idx & 3];
    s16[idx] = s;
    pmax = fmaxf(pmax, s);
  }
  if (!__all(pmax - S.m <= 8.f)) {  // rare slow path: real max growth
    float smax = fmaxf(pmax, __shfl_xor(pmax, 16));
    smax = fmaxf(smax, __shfl_xor(smax, 32));
    const float mnew = fmaxf(S.m, smax);
    const float fac = __builtin_amdgcn_exp2f(S.m - mnew);
    S.l *= fac;
    float fr[4];
#pragma unroll
    for (int r = 0; r < 4; ++r) fr[r] = __shfl(fac, g * 4 + r);
#pragma unroll
    for (int dc = 0; dc < 4; ++dc) {
      S.acc[dc][0] *= fr[0]; S.acc[dc][1] *= fr[1];
      S.acc[dc][2] *= fr[2]; S.acc[dc][3] *= fr[3];
    }
    S.m = mnew;
  }
  float psum = 0.f;
#pragma unroll
  for (int idx = 0; idx < 16; ++idx) {
    const float e = __builtin_amdgcn_exp2f(s16[idx] - S.m);  // masked -> +0
    s16[idx] = e;
    psum += e;
  }
  S.l += psum;  // per-lane partial; reduced across lanes at the end
  // PV through per-wave P buffer (two 32-k halves)
#pragma unroll
  for (int ks = 0; ks < 2; ++ks) {
    uint2 u0, u1;
    u0.x = cvtpk(s16[ks * 8 + 0], s16[ks * 8 + 1]);
    u0.y = cvtpk(s16[ks * 8 + 2], s16[ks * 8 + 3]);
    u1.x = cvtpk(s16[ks * 8 + 4], s16[ks * 8 + 5]);
    u1.y = cvtpk(s16[ks * 8 + 6], s16[ks * 8 + 7]);
    *(uint2*)&Pw[lq * 40 + g * 4] = u0;
    *(uint2*)&Pw[lq * 40 + 16 + g * 4] = u1;
    __builtin_amdgcn_wave_barrier();
    const bfx8 pa = *(const bfx8*)&Pw[lq * 40 + g * 8];
    __builtin_amdgcn_wave_barrier();
#pragma unroll
    for (int dc = 0; dc < 4; ++dc) {
      const int rowb = (dc * 16 + lq) * 128;
      const bfx8 vf = *(const bfx8*)&vbuf[rowb + ((ks * 64 + g * 16) ^ sw)];
      S.acc[dc] =
          __builtin_amdgcn_mfma_f32_16x16x32_bf16(pa, vf, S.acc[dc], 0, 0, 0);
    }
  }
}

__global__ __launch_bounds__(256, 2) void attn(
    const short* __restrict__ Q, const short* __restrict__ K,
    const short* __restrict__ VT, const unsigned short* __restrict__ pm,
    short* __restrict__ Y) {
  __shared__ char kv[2][16384];   // per buf: K tile 8KB | V^T tile 8KB
  __shared__ short P[4][16 * 40]; // per-wave P round-trip
  const int tid = threadIdx.x;
  const int w = tid >> 6, lane = tid & 63;
  const int lq = lane & 15, g = lane >> 4;
  const int bh = blockIdx.y, b = bh >> 4, h = bh & 15;
  const int tlo = blockIdx.x, thi = 31 - tlo;  // paired q-tiles
  const short* Qb = Q + (size_t)bh * TSEQ * DHEAD;
  const short* Kb = K + (size_t)bh * TSEQ * DHEAD;
  const short* Vb = VT + (size_t)bh * DHEAD * TSEQ;

  QPhase lo, hi;
  {
    const int qlo = tlo * 64 + w * 16 + lq;
    const int qhi = thi * 64 + w * 16 + lq;
    lo.qf0 = *(const bfx8*)(Qb + (size_t)qlo * DHEAD + g * 8);
    lo.qf1 = *(const bfx8*)(Qb + (size_t)qlo * DHEAD + 32 + g * 8);
    hi.qf0 = *(const bfx8*)(Qb + (size_t)qhi * DHEAD + g * 8);
    hi.qf1 = *(const bfx8*)(Qb + (size_t)qhi * DHEAD + 32 + g * 8);
#pragma unroll
    for (int dc = 0; dc < 4; ++dc) { lo.acc[dc] = f32x4{}; hi.acc[dc] = f32x4{}; }
    lo.m = -1e30f; lo.l = 0.f; hi.m = -1e30f; hi.l = 0.f;
    lo.pmr = pm + ((size_t)(b * TSEQ + qlo) << 7) + g;
    hi.pmr = pm + ((size_t)(b * TSEQ + qhi) << 7) + g;
  }

  const int sl = lane >> 3, sc = lane & 7;  // staging slot: row / col16
  const int ssw = (sc ^ sl) * 8;            // pre-swizzled source col (shorts)
  const int sw = (lq & 7) << 4;             // read-side XOR (bytes)

#define STAGE(bufn, k0s)                                                      \
  {                                                                           \
    _Pragma("unroll") for (int i = 0; i < 2; ++i) {                           \
      const int rr = w * 16 + i * 8;                                          \
      gload16(Kb + (size_t)((k0s) + rr + sl) * DHEAD + ssw,                   \
              &kv[bufn][rr * 128]);                                           \
      gload16(Vb + (size_t)(rr + sl) * TSEQ + (k0s) + ssw,                    \
              &kv[bufn][8192 + rr * 128]);                                    \
    }                                                                         \
  }

  STAGE(0, 0);
  __syncthreads();

  for (int t = 0; t <= thi; ++t) {
    const int buf = t & 1;
    if (t < thi) STAGE(buf ^ 1, (t + 1) * 64);
    const char* kbuf = kv[buf];
    const char* vbuf = kv[buf] + 8192;
    attn_tile(hi, kbuf, vbuf, P[w], t, sw, lq, g);
    if (t <= tlo) attn_tile(lo, kbuf, vbuf, P[w], t, sw, lq, g);
    __syncthreads();
  }

#pragma unroll
  for (int ph = 0; ph < 2; ++ph) {
    QPhase& S = ph ? hi : lo;
    const int q0 = (ph ? thi : tlo) * 64 + w * 16;
    float lr = S.l;  // per-lane partials -> row sum
    lr += __shfl_xor(lr, 16);
    lr += __shfl_xor(lr, 32);
    float li[4];
#pragma unroll
    for (int r = 0; r < 4; ++r) {
      const float lv = __shfl(lr, g * 4 + r);
      li[r] = lv > 0.f ? 1.f / lv : 0.f;
    }
#pragma unroll
    for (int dc = 0; dc < 4; ++dc)
#pragma unroll
      for (int r = 0; r < 4; ++r) {
        const int t = q0 + g * 4 + r;
        Y[((size_t)b * TSEQ + t) * CDIM + h * DHEAD + dc * 16 + lq] =
            (short)f2bf(S.acc[dc][r] * li[r]);
      }
  }
#undef STAGE
}

extern "C" void kernel_launch(void* const* d_in, const int* in_sizes, int n_in,
                              void* d_out, int out_size, void* d_ws,
                              size_t ws_size, hipStream_t stream) {
  const float* x = (const float*)d_in[0];
  const unsigned char* dyn = (const unsigned char*)d_in[1];
  const unsigned char* causal = (const unsigned char*)d_in[2];
  const float* Wq = (const float*)d_in[3];
  const float* bq = (const float*)d_in[4];
  const float* Wk = (const float*)d_in[5];
  const float* bk = (const float*)d_in[6];
  const float* Wv = (const float*)d_in[7];
  const float* bv = (const float*)d_in[8];
  const float* Wo = (const float*)d_in[9];
  const float* bo = (const float*)d_in[10];

  char* ws = (char*)d_ws;
  const size_t MB8 = 8ull * 1024 * 1024;
  short* xb = (short*)(ws + 0 * MB8);
  short* wall = (short*)(ws + 1 * MB8);  // Wq,Wk,Wv,Wo bf16 concatenated
  short* Qb = (short*)(ws + 2 * MB8);
  short* Kb = (short*)(ws + 3 * MB8);
  short* Vb = (short*)(ws + 4 * MB8);
  short* VTb = (short*)(ws + 5 * MB8);
  short* Yb = (short*)(ws + 6 * MB8);
  unsigned long long* pmask = (unsigned long long*)(ws + 7 * MB8);  // 1 MB

  convert_all<<<dim3(4096, 5), 256, 0, stream>>>(x, Wq, Wk, Wv, Wo, xb, wall);
  maskpack<<<dim3(512), 256, 0, stream>>>(dyn, causal, pmask);
  gemm_nt<0><<<dim3(32, 8, 3), 256, 0, stream>>>(xb, wall, bq, bk, bv, Qb, Kb,
                                                 Vb, nullptr);
  vtrans<<<dim3(32, 32), 256, 0, stream>>>(Vb, VTb);
  attn<<<dim3(16, 32), 256, 0, stream>>>(Qb, Kb, VTb,
                                         (const unsigned short*)pmask, Yb);
  gemm_nt<1><<<dim3(32, 8, 1), 256, 0, stream>>>(Yb, wall, bo, nullptr, nullptr,
                                                 nullptr, nullptr, nullptr,
                                                 (float*)d_out);
}

// Round 6
// 154.069 us; speedup vs baseline: 1.1035x; 1.1035x over previous
//
#include <hip/hip_runtime.h>

#define TSEQ 2048
#define NHEAD 16
#define DHEAD 64
#define CDIM 1024
#define BATCH 2

typedef __attribute__((ext_vector_type(8))) short bfx8;
typedef __attribute__((ext_vector_type(4))) short bfx4;
typedef __attribute__((ext_vector_type(4))) float f32x4;

__device__ __forceinline__ unsigned short f2bf(float f) {
  unsigned u = __builtin_bit_cast(unsigned, f);
  u += 0x7fffu + ((u >> 16) & 1u);
  return (unsigned short)(u >> 16);
}

__device__ __forceinline__ unsigned cvtpk(float lo, float hi) {
  unsigned r;
  asm("v_cvt_pk_bf16_f32 %0, %1, %2" : "=v"(r) : "v"(lo), "v"(hi));
  return r;
}

__device__ __forceinline__ float max3f(float a, float b, float c) {
  float d;
  asm("v_max3_f32 %0, %1, %2, %3" : "=v"(d) : "v"(a), "v"(b), "v"(c));
  return d;
}

__device__ __forceinline__ void gload16(const void* g, void* l) {
  __builtin_amdgcn_global_load_lds(
      (const __attribute__((address_space(1))) unsigned*)g,
      (__attribute__((address_space(3))) unsigned*)l, 16, 0, 0);
}

// ---------------- elementwise fp32 -> bf16 conversion (x + 4 weights) -------
__global__ __launch_bounds__(256) void convert_all(
    const float* __restrict__ x,
    const float* __restrict__ wq, const float* __restrict__ wk,
    const float* __restrict__ wv, const float* __restrict__ wo,
    short* __restrict__ xb, short* __restrict__ wall) {
  const int y = blockIdx.y;
  const float* src;
  short* dst;
  int n;
  if (y == 0) { src = x; dst = xb; n = (BATCH * TSEQ * CDIM) / 4; }
  else {
    src = (y == 1) ? wq : (y == 2) ? wk : (y == 3) ? wv : wo;
    dst = wall + (size_t)(y - 1) * CDIM * CDIM;
    n = (CDIM * CDIM) / 4;
  }
  const int i = blockIdx.x * 256 + threadIdx.x;
  if (i < n) {
    const float4 v = ((const float4*)src)[i];
    bfx4 o;
    o[0] = (short)f2bf(v.x); o[1] = (short)f2bf(v.y);
    o[2] = (short)f2bf(v.z); o[3] = (short)f2bf(v.w);
    ((bfx4*)dst)[i] = o;
  }
}

// ---------------- combined mask pre-pack (ballot, 1 wave per u64) -----------
// pm[gid], gid=(b*T+q)*32+tile; bit l (= g*16+blk*4+r) set => k =
// tile*64 + blk*16+g*4+r is MASKED for row q. Lane l evaluates bit l: its
// load covers one int32/byte of a contiguous 256B/64B segment -> coalesced.
__global__ __launch_bounds__(256) void maskpack(
    const unsigned char* __restrict__ dyn,
    const unsigned char* __restrict__ causal,
    unsigned long long* __restrict__ pm) {
  const bool mbyte = (causal[32] != 0);  // dyn dtype probe (bool-as-byte?)
  const int wave = threadIdx.x >> 6, lane = threadIdx.x & 63;
  const int gid = blockIdx.x * 4 + wave;
  const int tile = gid & 31;
  const int q = (gid >> 5) & (TSEQ - 1);
  const int b = gid >> 16;
  const int g = lane >> 4, blk = (lane >> 2) & 3, r = lane & 3;
  const int k = tile * 64 + blk * 16 + g * 4 + r;
  const size_t off = ((size_t)b * TSEQ + q) * TSEQ + k;
  const bool dm = mbyte ? (dyn[off] != 0) : (((const int*)dyn)[off] != 0);
  const bool qok = (q & 3) != 3;
  const bool al =
      (((k >> 5) == (q >> 5)) || ((k <= q) && qok && (r != 3))) && !dm;
  const unsigned long long bal = __ballot(!al);
  if (lane == 0) pm[gid] = bal;
}

// ---------------- NT GEMM (A[M][K] bf16, B[N][K] bf16), 128x128 tile --------
template <int MODE>
__global__ __launch_bounds__(256) void gemm_nt(
    const short* __restrict__ A, const short* __restrict__ Ball,
    const float* __restrict__ bias0, const float* __restrict__ bias1,
    const float* __restrict__ bias2,
    short* __restrict__ Oq, short* __restrict__ Ok, short* __restrict__ Ov,
    float* __restrict__ Of) {
  __shared__ short As[128 * 32];
  __shared__ short Bs[128 * 32];
  const int tid = threadIdx.x;
  const int w = tid >> 6, lane = tid & 63;
  const int lq = lane & 15, g = lane >> 4;
  const int wr = w >> 1, wc = w & 1;
  const int m0 = blockIdx.x * 128, n0 = blockIdx.y * 128;
  const int which = (MODE == 0) ? (int)blockIdx.z : 3;
  const short* B = Ball + (size_t)which * CDIM * CDIM;
  f32x4 acc[4][4] = {};
  for (int kt = 0; kt < CDIM / 32; ++kt) {
#pragma unroll
    for (int ph = 0; ph < 2; ++ph) {
      const int c = ph * 256 + tid;  // chunk: row=c>>2, k-part=(c&3)*8
      gload16(A + (size_t)(m0 + (c >> 2)) * CDIM + kt * 32 + (c & 3) * 8,
              As + (size_t)(ph * 256 + w * 64) * 8);
      gload16(B + (size_t)(n0 + (c >> 2)) * CDIM + kt * 32 + (c & 3) * 8,
              Bs + (size_t)(ph * 256 + w * 64) * 8);
    }
    __syncthreads();
    bfx8 af[4], bfr[4];
#pragma unroll
    for (int i = 0; i < 4; ++i)
      af[i] = *(const bfx8*)&As[(wr * 64 + i * 16 + lq) * 32 + g * 8];
#pragma unroll
    for (int i = 0; i < 4; ++i)
      bfr[i] = *(const bfx8*)&Bs[(wc * 64 + i * 16 + lq) * 32 + g * 8];
#pragma unroll
    for (int i = 0; i < 4; ++i)
#pragma unroll
      for (int j = 0; j < 4; ++j)
        acc[i][j] = __builtin_amdgcn_mfma_f32_16x16x32_bf16(af[i], bfr[j],
                                                            acc[i][j], 0, 0, 0);
    __syncthreads();
  }
  if (MODE == 0) {
    const float* bias = (which == 0) ? bias0 : (which == 1) ? bias1 : bias2;
    const float scale = (which == 0) ? 0.18033688011112042f : 1.0f;
    short* O = (which == 0) ? Oq : (which == 1) ? Ok : Ov;
#pragma unroll
    for (int i = 0; i < 4; ++i)
#pragma unroll
      for (int j = 0; j < 4; ++j) {
        const int col = n0 + wc * 64 + j * 16 + lq;  // c = h*64+d
        const int h = col >> 6, d = col & 63;
        const float bb = bias[col];
#pragma unroll
        for (int r = 0; r < 4; ++r) {
          const int row = m0 + wr * 64 + i * 16 + g * 4 + r;  // b*T+t
          const int b_ = row >> 11, t = row & (TSEQ - 1);
          O[(((size_t)b_ * NHEAD + h) * TSEQ + t) * DHEAD + d] =
              (short)f2bf((acc[i][j][r] + bb) * scale);
        }
      }
  } else {
    const float* bias = bias0;
#pragma unroll
    for (int i = 0; i < 4; ++i)
#pragma unroll
      for (int j = 0; j < 4; ++j) {
        const int col = n0 + wc * 64 + j * 16 + lq;
        const float bb = bias[col];
#pragma unroll
        for (int r = 0; r < 4; ++r) {
          const int row = m0 + wr * 64 + i * 16 + g * 4 + r;
          Of[(size_t)row * CDIM + col] = acc[i][j][r] + bb;
        }
      }
  }
}

// ---------------- V (b,h,t,d) -> VT (b,h,d,t) -------------------------------
__global__ __launch_bounds__(256) void vtrans(const short* __restrict__ V,
                                              short* __restrict__ VT) {
  __shared__ short tile[64][72];
  const int bh = blockIdx.y;
  const int t0 = blockIdx.x * 64;
  const int tid = threadIdx.x;
  const short* src = V + ((size_t)bh * TSEQ + t0) * DHEAD;
#pragma unroll
  for (int ph = 0; ph < 4; ++ph) {
    const int c = ph * 256 + tid;
    const int row = c >> 4, col = (c & 15) * 4;
    *(bfx4*)&tile[row][col] = *(const bfx4*)(src + row * DHEAD + col);
  }
  __syncthreads();
  short* dst = VT + (size_t)bh * DHEAD * TSEQ + t0;
#pragma unroll
  for (int ph = 0; ph < 4; ++ph) {
    const int c = ph * 256 + tid;
    const int d = c >> 4, tc = (c & 15) * 4;
    bfx4 o;
    o[0] = tile[tc][d]; o[1] = tile[tc + 1][d];
    o[2] = tile[tc + 2][d]; o[3] = tile[tc + 3][d];
    *(bfx4*)(dst + (size_t)d * TSEQ + tc) = o;
  }
}

// ---------------- fused flash attention v5 ----------------------------------
// v4 + single P LDS round-trip per tile-phase (write all 64 cols, one
// wave_barrier, two ds_read_b128) and v_max3 tree for pmax.
struct QPhase {
  bfx8 qf0, qf1;
  f32x4 acc[4];
  float m, l;
  const unsigned short* pmr;  // packed-mask base for (b,q,g)
};

__device__ __forceinline__ void attn_tile(QPhase& S, const char* kbuf,
                                          const char* vbuf, short* Pw,
                                          int t, int sw, int lq, int g) {
  const unsigned mbits = S.pmr[t << 2];  // bit idx set => masked
  // QK^T (S^T quadrants)
  f32x4 st[4] = {};
#pragma unroll
  for (int blk = 0; blk < 4; ++blk) {
    const int rowb = (blk * 16 + lq) * 128;
    const bfx8 kf0 = *(const bfx8*)&kbuf[rowb + ((g * 16) ^ sw)];
    const bfx8 kf1 = *(const bfx8*)&kbuf[rowb + ((64 + g * 16) ^ sw)];
    st[blk] =
        __builtin_amdgcn_mfma_f32_16x16x32_bf16(kf0, S.qf0, st[blk], 0, 0, 0);
    st[blk] =
        __builtin_amdgcn_mfma_f32_16x16x32_bf16(kf1, S.qf1, st[blk], 0, 0, 0);
  }
  float s16[16];
#pragma unroll
  for (int idx = 0; idx < 16; ++idx)
    s16[idx] = ((mbits >> idx) & 1u) ? -3.0e38f : st[idx >> 2][idx & 3];
  // max over 16 via v_max3 tree (depth 3)
  const float t0 = max3f(s16[0], s16[1], s16[2]);
  const float t1 = max3f(s16[3], s16[4], s16[5]);
  const float t2 = max3f(s16[6], s16[7], s16[8]);
  const float t3 = max3f(s16[9], s16[10], s16[11]);
  const float t4 = max3f(s16[12], s16[13], s16[14]);
  const float pmax = fmaxf(max3f(t0, t1, t2), max3f(t3, t4, s16[15]));
  if (!__all(pmax - S.m <= 8.f)) {  // rare slow path: real max growth
    float smax = fmaxf(pmax, __shfl_xor(pmax, 16));
    smax = fmaxf(smax, __shfl_xor(smax, 32));
    const float mnew = fmaxf(S.m, smax);
    const float fac = __builtin_amdgcn_exp2f(S.m - mnew);
    S.l *= fac;
    float fr[4];
#pragma unroll
    for (int r = 0; r < 4; ++r) fr[r] = __shfl(fac, g * 4 + r);
#pragma unroll
    for (int dc = 0; dc < 4; ++dc) {
      S.acc[dc][0] *= fr[0]; S.acc[dc][1] *= fr[1];
      S.acc[dc][2] *= fr[2]; S.acc[dc][3] *= fr[3];
    }
    S.m = mnew;
  }
  float psum = 0.f;
#pragma unroll
  for (int idx = 0; idx < 16; ++idx) {
    const float e = __builtin_amdgcn_exp2f(s16[idx] - S.m);  // masked -> +0
    s16[idx] = e;
    psum += e;
  }
  S.l += psum;  // per-lane partial; reduced across lanes at the end
  // P -> LDS once (all 64 cols), read both 32-k halves back
#pragma unroll
  for (int blk = 0; blk < 4; ++blk) {
    uint2 u;
    u.x = cvtpk(s16[blk * 4 + 0], s16[blk * 4 + 1]);
    u.y = cvtpk(s16[blk * 4 + 2], s16[blk * 4 + 3]);
    *(uint2*)&Pw[lq * 72 + blk * 16 + g * 4] = u;
  }
  __builtin_amdgcn_wave_barrier();
  const bfx8 pa0 = *(const bfx8*)&Pw[lq * 72 + g * 8];
  const bfx8 pa1 = *(const bfx8*)&Pw[lq * 72 + 32 + g * 8];
  __builtin_amdgcn_wave_barrier();
#pragma unroll
  for (int dc = 0; dc < 4; ++dc) {
    const int rowb = (dc * 16 + lq) * 128;
    const bfx8 vf0 = *(const bfx8*)&vbuf[rowb + ((g * 16) ^ sw)];
    const bfx8 vf1 = *(const bfx8*)&vbuf[rowb + ((64 + g * 16) ^ sw)];
    S.acc[dc] =
        __builtin_amdgcn_mfma_f32_16x16x32_bf16(pa0, vf0, S.acc[dc], 0, 0, 0);
    S.acc[dc] =
        __builtin_amdgcn_mfma_f32_16x16x32_bf16(pa1, vf1, S.acc[dc], 0, 0, 0);
  }
}

__global__ __launch_bounds__(256, 2) void attn(
    const short* __restrict__ Q, const short* __restrict__ K,
    const short* __restrict__ VT, const unsigned short* __restrict__ pm,
    short* __restrict__ Y) {
  __shared__ char kv[2][16384];    // per buf: K tile 8KB | V^T tile 8KB
  __shared__ short P[4][16 * 72];  // per-wave P round-trip (64 cols, pad 8)
  const int tid = threadIdx.x;
  const int w = tid >> 6, lane = tid & 63;
  const int lq = lane & 15, g = lane >> 4;
  const int bh = blockIdx.y, b = bh >> 4, h = bh & 15;
  const int tlo = blockIdx.x, thi = 31 - tlo;  // paired q-tiles
  const short* Qb = Q + (size_t)bh * TSEQ * DHEAD;
  const short* Kb = K + (size_t)bh * TSEQ * DHEAD;
  const short* Vb = VT + (size_t)bh * DHEAD * TSEQ;

  QPhase lo, hi;
  {
    const int qlo = tlo * 64 + w * 16 + lq;
    const int qhi = thi * 64 + w * 16 + lq;
    lo.qf0 = *(const bfx8*)(Qb + (size_t)qlo * DHEAD + g * 8);
    lo.qf1 = *(const bfx8*)(Qb + (size_t)qlo * DHEAD + 32 + g * 8);
    hi.qf0 = *(const bfx8*)(Qb + (size_t)qhi * DHEAD + g * 8);
    hi.qf1 = *(const bfx8*)(Qb + (size_t)qhi * DHEAD + 32 + g * 8);
#pragma unroll
    for (int dc = 0; dc < 4; ++dc) { lo.acc[dc] = f32x4{}; hi.acc[dc] = f32x4{}; }
    lo.m = -1e30f; lo.l = 0.f; hi.m = -1e30f; hi.l = 0.f;
    lo.pmr = pm + ((size_t)(b * TSEQ + qlo) << 7) + g;
    hi.pmr = pm + ((size_t)(b * TSEQ + qhi) << 7) + g;
  }

  const int sl = lane >> 3, sc = lane & 7;  // staging slot: row / col16
  const int ssw = (sc ^ sl) * 8;            // pre-swizzled source col (shorts)
  const int sw = (lq & 7) << 4;             // read-side XOR (bytes)

#define STAGE(bufn, k0s)                                                      \
  {                                                                           \
    _Pragma("unroll") for (int i = 0; i < 2; ++i) {                           \
      const int rr = w * 16 + i * 8;                                          \
      gload16(Kb + (size_t)((k0s) + rr + sl) * DHEAD + ssw,                   \
              &kv[bufn][rr * 128]);                                           \
      gload16(Vb + (size_t)(rr + sl) * TSEQ + (k0s) + ssw,                    \
              &kv[bufn][8192 + rr * 128]);                                    \
    }                                                                         \
  }

  STAGE(0, 0);
  __syncthreads();

  for (int t = 0; t <= thi; ++t) {
    const int buf = t & 1;
    if (t < thi) STAGE(buf ^ 1, (t + 1) * 64);
    const char* kbuf = kv[buf];
    const char* vbuf = kv[buf] + 8192;
    attn_tile(hi, kbuf, vbuf, P[w], t, sw, lq, g);
    if (t <= tlo) attn_tile(lo, kbuf, vbuf, P[w], t, sw, lq, g);
    __syncthreads();
  }

#pragma unroll
  for (int ph = 0; ph < 2; ++ph) {
    QPhase& S = ph ? hi : lo;
    const int q0 = (ph ? thi : tlo) * 64 + w * 16;
    float lr = S.l;  // per-lane partials -> row sum
    lr += __shfl_xor(lr, 16);
    lr += __shfl_xor(lr, 32);
    float li[4];
#pragma unroll
    for (int r = 0; r < 4; ++r) {
      const float lv = __shfl(lr, g * 4 + r);
      li[r] = lv > 0.f ? 1.f / lv : 0.f;
    }
#pragma unroll
    for (int dc = 0; dc < 4; ++dc)
#pragma unroll
      for (int r = 0; r < 4; ++r) {
        const int t = q0 + g * 4 + r;
        Y[((size_t)b * TSEQ + t) * CDIM + h * DHEAD + dc * 16 + lq] =
            (short)f2bf(S.acc[dc][r] * li[r]);
      }
  }
#undef STAGE
}

extern "C" void kernel_launch(void* const* d_in, const int* in_sizes, int n_in,
                              void* d_out, int out_size, void* d_ws,
                              size_t ws_size, hipStream_t stream) {
  const float* x = (const float*)d_in[0];
  const unsigned char* dyn = (const unsigned char*)d_in[1];
  const unsigned char* causal = (const unsigned char*)d_in[2];
  const float* Wq = (const float*)d_in[3];
  const float* bq = (const float*)d_in[4];
  const float* Wk = (const float*)d_in[5];
  const float* bk = (const float*)d_in[6];
  const float* Wv = (const float*)d_in[7];
  const float* bv = (const float*)d_in[8];
  const float* Wo = (const float*)d_in[9];
  const float* bo = (const float*)d_in[10];

  char* ws = (char*)d_ws;
  const size_t MB8 = 8ull * 1024 * 1024;
  short* xb = (short*)(ws + 0 * MB8);
  short* wall = (short*)(ws + 1 * MB8);  // Wq,Wk,Wv,Wo bf16 concatenated
  short* Qb = (short*)(ws + 2 * MB8);
  short* Kb = (short*)(ws + 3 * MB8);
  short* Vb = (short*)(ws + 4 * MB8);
  short* VTb = (short*)(ws + 5 * MB8);
  short* Yb = (short*)(ws + 6 * MB8);
  unsigned long long* pmask = (unsigned long long*)(ws + 7 * MB8);  // 1 MB

  convert_all<<<dim3(4096, 5), 256, 0, stream>>>(x, Wq, Wk, Wv, Wo, xb, wall);
  maskpack<<<dim3(32768), 256, 0, stream>>>(dyn, causal, pmask);
  gemm_nt<0><<<dim3(32, 8, 3), 256, 0, stream>>>(xb, wall, bq, bk, bv, Qb, Kb,
                                                 Vb, nullptr);
  vtrans<<<dim3(32, 32), 256, 0, stream>>>(Vb, VTb);
  attn<<<dim3(16, 32), 256, 0, stream>>>(Qb, Kb, VTb,
                                         (const unsigned short*)pmask, Yb);
  gemm_nt<1><<<dim3(32, 8, 1), 256, 0, stream>>>(Yb, wall, bo, nullptr, nullptr,
                                                 nullptr, nullptr, nullptr,
                                                 (float*)d_out);
}

// Round 7
// 153.285 us; speedup vs baseline: 1.1092x; 1.0051x over previous
//
#include <hip/hip_runtime.h>

#define TSEQ 2048
#define NHEAD 16
#define DHEAD 64
#define CDIM 1024
#define BATCH 2

typedef __attribute__((ext_vector_type(8))) short bfx8;
typedef __attribute__((ext_vector_type(4))) short bfx4;
typedef __attribute__((ext_vector_type(4))) float f32x4;

__device__ __forceinline__ unsigned short f2bf(float f) {
  unsigned u = __builtin_bit_cast(unsigned, f);
  u += 0x7fffu + ((u >> 16) & 1u);
  return (unsigned short)(u >> 16);
}

__device__ __forceinline__ unsigned cvtpk(float lo, float hi) {
  unsigned r;
  asm("v_cvt_pk_bf16_f32 %0, %1, %2" : "=v"(r) : "v"(lo), "v"(hi));
  return r;
}

__device__ __forceinline__ float max3f(float a, float b, float c) {
  float d;
  asm("v_max3_f32 %0, %1, %2, %3" : "=v"(d) : "v"(a), "v"(b), "v"(c));
  return d;
}

__device__ __forceinline__ void gload16(const void* g, void* l) {
  __builtin_amdgcn_global_load_lds(
      (const __attribute__((address_space(1))) unsigned*)g,
      (__attribute__((address_space(3))) unsigned*)l, 16, 0, 0);
}

// ---------------- elementwise fp32 -> bf16 conversion (x + 4 weights) -------
__global__ __launch_bounds__(256) void convert_all(
    const float* __restrict__ x,
    const float* __restrict__ wq, const float* __restrict__ wk,
    const float* __restrict__ wv, const float* __restrict__ wo,
    short* __restrict__ xb, short* __restrict__ wall) {
  const int y = blockIdx.y;
  const float* src;
  short* dst;
  int n;
  if (y == 0) { src = x; dst = xb; n = (BATCH * TSEQ * CDIM) / 4; }
  else {
    src = (y == 1) ? wq : (y == 2) ? wk : (y == 3) ? wv : wo;
    dst = wall + (size_t)(y - 1) * CDIM * CDIM;
    n = (CDIM * CDIM) / 4;
  }
  const int i = blockIdx.x * 256 + threadIdx.x;
  if (i < n) {
    const float4 v = ((const float4*)src)[i];
    bfx4 o;
    o[0] = (short)f2bf(v.x); o[1] = (short)f2bf(v.y);
    o[2] = (short)f2bf(v.z); o[3] = (short)f2bf(v.w);
    ((bfx4*)dst)[i] = o;
  }
}

// ---------------- combined mask pre-pack (ballot, 1 wave per u64) -----------
__global__ __launch_bounds__(256) void maskpack(
    const unsigned char* __restrict__ dyn,
    const unsigned char* __restrict__ causal,
    unsigned long long* __restrict__ pm) {
  const bool mbyte = (causal[32] != 0);  // dyn dtype probe (bool-as-byte?)
  const int wave = threadIdx.x >> 6, lane = threadIdx.x & 63;
  const int gid = blockIdx.x * 4 + wave;
  const int tile = gid & 31;
  const int q = (gid >> 5) & (TSEQ - 1);
  const int b = gid >> 16;
  const int g = lane >> 4, blk = (lane >> 2) & 3, r = lane & 3;
  const int k = tile * 64 + blk * 16 + g * 4 + r;
  const size_t off = ((size_t)b * TSEQ + q) * TSEQ + k;
  const bool dm = mbyte ? (dyn[off] != 0) : (((const int*)dyn)[off] != 0);
  const bool qok = (q & 3) != 3;
  const bool al =
      (((k >> 5) == (q >> 5)) || ((k <= q) && qok && (r != 3))) && !dm;
  const unsigned long long bal = __ballot(!al);
  if (lane == 0) pm[gid] = bal;
}

// ---------------- NT GEMM, 128x128 tile, double-buffered prefetch -----------
template <int MODE>
__global__ __launch_bounds__(256) void gemm_nt(
    const short* __restrict__ A, const short* __restrict__ Ball,
    const float* __restrict__ bias0, const float* __restrict__ bias1,
    const float* __restrict__ bias2,
    short* __restrict__ Oq, short* __restrict__ Ok, short* __restrict__ Ov,
    float* __restrict__ Of) {
  __shared__ short As[2][128 * 32];
  __shared__ short Bs[2][128 * 32];
  const int tid = threadIdx.x;
  const int w = tid >> 6, lane = tid & 63;
  const int lq = lane & 15, g = lane >> 4;
  const int wr = w >> 1, wc = w & 1;
  const int m0 = blockIdx.x * 128, n0 = blockIdx.y * 128;
  const int which = (MODE == 0) ? (int)blockIdx.z : 3;
  const short* B = Ball + (size_t)which * CDIM * CDIM;

#define GS(bi, kt)                                                             \
  {                                                                            \
    _Pragma("unroll") for (int ph = 0; ph < 2; ++ph) {                         \
      const int c = ph * 256 + tid;                                            \
      gload16(A + (size_t)(m0 + (c >> 2)) * CDIM + (kt) * 32 + (c & 3) * 8,    \
              &As[bi][(ph * 256 + w * 64) * 8]);                               \
      gload16(B + (size_t)(n0 + (c >> 2)) * CDIM + (kt) * 32 + (c & 3) * 8,    \
              &Bs[bi][(ph * 256 + w * 64) * 8]);                               \
    }                                                                          \
  }

  GS(0, 0);
  __syncthreads();
  f32x4 acc[4][4] = {};
  for (int kt = 0; kt < CDIM / 32; ++kt) {
    const int bi = kt & 1;
    if (kt + 1 < CDIM / 32) GS(bi ^ 1, kt + 1);
    bfx8 af[4], bfr[4];
#pragma unroll
    for (int i = 0; i < 4; ++i)
      af[i] = *(const bfx8*)&As[bi][(wr * 64 + i * 16 + lq) * 32 + g * 8];
#pragma unroll
    for (int i = 0; i < 4; ++i)
      bfr[i] = *(const bfx8*)&Bs[bi][(wc * 64 + i * 16 + lq) * 32 + g * 8];
#pragma unroll
    for (int i = 0; i < 4; ++i)
#pragma unroll
      for (int j = 0; j < 4; ++j)
        acc[i][j] = __builtin_amdgcn_mfma_f32_16x16x32_bf16(af[i], bfr[j],
                                                            acc[i][j], 0, 0, 0);
    __syncthreads();
  }
#undef GS
  if (MODE == 0) {
    const float* bias = (which == 0) ? bias0 : (which == 1) ? bias1 : bias2;
    const float scale = (which == 0) ? 0.18033688011112042f : 1.0f;
    short* O = (which == 0) ? Oq : (which == 1) ? Ok : Ov;
#pragma unroll
    for (int i = 0; i < 4; ++i)
#pragma unroll
      for (int j = 0; j < 4; ++j) {
        const int col = n0 + wc * 64 + j * 16 + lq;  // c = h*64+d
        const int h = col >> 6, d = col & 63;
        const float bb = bias[col];
#pragma unroll
        for (int r = 0; r < 4; ++r) {
          const int row = m0 + wr * 64 + i * 16 + g * 4 + r;  // b*T+t
          const int b_ = row >> 11, t = row & (TSEQ - 1);
          O[(((size_t)b_ * NHEAD + h) * TSEQ + t) * DHEAD + d] =
              (short)f2bf((acc[i][j][r] + bb) * scale);
        }
      }
  } else {
    const float* bias = bias0;
#pragma unroll
    for (int i = 0; i < 4; ++i)
#pragma unroll
      for (int j = 0; j < 4; ++j) {
        const int col = n0 + wc * 64 + j * 16 + lq;
        const float bb = bias[col];
#pragma unroll
        for (int r = 0; r < 4; ++r) {
          const int row = m0 + wr * 64 + i * 16 + g * 4 + r;
          Of[(size_t)row * CDIM + col] = acc[i][j][r] + bb;
        }
      }
  }
}

// ---------------- V (b,h,t,d) -> VT (b,h,d,t) -------------------------------
__global__ __launch_bounds__(256) void vtrans(const short* __restrict__ V,
                                              short* __restrict__ VT) {
  __shared__ short tile[64][72];
  const int bh = blockIdx.y;
  const int t0 = blockIdx.x * 64;
  const int tid = threadIdx.x;
  const short* src = V + ((size_t)bh * TSEQ + t0) * DHEAD;
#pragma unroll
  for (int ph = 0; ph < 4; ++ph) {
    const int c = ph * 256 + tid;
    const int row = c >> 4, col = (c & 15) * 4;
    *(bfx4*)&tile[row][col] = *(const bfx4*)(src + row * DHEAD + col);
  }
  __syncthreads();
  short* dst = VT + (size_t)bh * DHEAD * TSEQ + t0;
#pragma unroll
  for (int ph = 0; ph < 4; ++ph) {
    const int c = ph * 256 + tid;
    const int d = c >> 4, tc = (c & 15) * 4;
    bfx4 o;
    o[0] = tile[tc][d]; o[1] = tile[tc + 1][d];
    o[2] = tile[tc + 2][d]; o[3] = tile[tc + 3][d];
    *(bfx4*)(dst + (size_t)d * TSEQ + tc) = o;
  }
}

// ---------------- fused flash attention v6 ----------------------------------
// v5 + interleaved hi/lo q-streams in one pass (2-way ILP through the whole
// QK->softmax->PV chain, K/V fragments ds_read once and fed to both streams,
// one shared wave_barrier) + s_setprio(1) around the MFMA clusters (T5).
struct QPhase {
  bfx8 qf0, qf1;
  f32x4 acc[4];
  float m, l;
  const unsigned short* pmr;  // packed-mask base for (b,q,g)
};

__device__ __forceinline__ void softmax16(QPhase& S, f32x4* st, unsigned mbits,
                                          float* s16, int g) {
#pragma unroll
  for (int idx = 0; idx < 16; ++idx)
    s16[idx] = ((mbits >> idx) & 1u) ? -3.0e38f : st[idx >> 2][idx & 3];
  const float t0 = max3f(s16[0], s16[1], s16[2]);
  const float t1 = max3f(s16[3], s16[4], s16[5]);
  const float t2 = max3f(s16[6], s16[7], s16[8]);
  const float t3 = max3f(s16[9], s16[10], s16[11]);
  const float t4 = max3f(s16[12], s16[13], s16[14]);
  const float pmax = fmaxf(max3f(t0, t1, t2), max3f(t3, t4, s16[15]));
  if (!__all(pmax - S.m <= 8.f)) {  // rare slow path: real max growth
    float smax = fmaxf(pmax, __shfl_xor(pmax, 16));
    smax = fmaxf(smax, __shfl_xor(smax, 32));
    const float mnew = fmaxf(S.m, smax);
    const float fac = __builtin_amdgcn_exp2f(S.m - mnew);
    S.l *= fac;
    float fr[4];
#pragma unroll
    for (int r = 0; r < 4; ++r) fr[r] = __shfl(fac, g * 4 + r);
#pragma unroll
    for (int dc = 0; dc < 4; ++dc) {
      S.acc[dc][0] *= fr[0]; S.acc[dc][1] *= fr[1];
      S.acc[dc][2] *= fr[2]; S.acc[dc][3] *= fr[3];
    }
    S.m = mnew;
  }
  float psum = 0.f;
#pragma unroll
  for (int idx = 0; idx < 16; ++idx) {
    const float e = __builtin_amdgcn_exp2f(s16[idx] - S.m);  // masked -> +0
    s16[idx] = e;
    psum += e;
  }
  S.l += psum;
}

__device__ __forceinline__ void attn_tile2(QPhase& A, QPhase& B, bool doB,
                                           const char* kbuf, const char* vbuf,
                                           short* PwA, short* PwB, int t,
                                           int sw, int lq, int g) {
  const unsigned mbA = A.pmr[t << 2];
  const unsigned mbB = doB ? B.pmr[t << 2] : 0u;
  // QK^T for both streams; K fragments read once
  f32x4 stA[4] = {}, stB[4] = {};
  __builtin_amdgcn_s_setprio(1);
#pragma unroll
  for (int blk = 0; blk < 4; ++blk) {
    const int rowb = (blk * 16 + lq) * 128;
    const bfx8 kf0 = *(const bfx8*)&kbuf[rowb + ((g * 16) ^ sw)];
    const bfx8 kf1 = *(const bfx8*)&kbuf[rowb + ((64 + g * 16) ^ sw)];
    stA[blk] =
        __builtin_amdgcn_mfma_f32_16x16x32_bf16(kf0, A.qf0, stA[blk], 0, 0, 0);
    stA[blk] =
        __builtin_amdgcn_mfma_f32_16x16x32_bf16(kf1, A.qf1, stA[blk], 0, 0, 0);
    if (doB) {
      stB[blk] = __builtin_amdgcn_mfma_f32_16x16x32_bf16(kf0, B.qf0, stB[blk],
                                                         0, 0, 0);
      stB[blk] = __builtin_amdgcn_mfma_f32_16x16x32_bf16(kf1, B.qf1, stB[blk],
                                                         0, 0, 0);
    }
  }
  __builtin_amdgcn_s_setprio(0);
  // online softmax, both streams
  float sA[16], sB[16];
  softmax16(A, stA, mbA, sA, g);
  if (doB) softmax16(B, stB, mbB, sB, g);
  // P -> LDS (both), one wave_barrier, read back, PV (V fragments read once)
#pragma unroll
  for (int blk = 0; blk < 4; ++blk) {
    uint2 u;
    u.x = cvtpk(sA[blk * 4 + 0], sA[blk * 4 + 1]);
    u.y = cvtpk(sA[blk * 4 + 2], sA[blk * 4 + 3]);
    *(uint2*)&PwA[lq * 72 + blk * 16 + g * 4] = u;
  }
  if (doB) {
#pragma unroll
    for (int blk = 0; blk < 4; ++blk) {
      uint2 u;
      u.x = cvtpk(sB[blk * 4 + 0], sB[blk * 4 + 1]);
      u.y = cvtpk(sB[blk * 4 + 2], sB[blk * 4 + 3]);
      *(uint2*)&PwB[lq * 72 + blk * 16 + g * 4] = u;
    }
  }
  __builtin_amdgcn_wave_barrier();
  const bfx8 paA0 = *(const bfx8*)&PwA[lq * 72 + g * 8];
  const bfx8 paA1 = *(const bfx8*)&PwA[lq * 72 + 32 + g * 8];
  bfx8 paB0, paB1;
  if (doB) {
    paB0 = *(const bfx8*)&PwB[lq * 72 + g * 8];
    paB1 = *(const bfx8*)&PwB[lq * 72 + 32 + g * 8];
  }
  __builtin_amdgcn_wave_barrier();
  __builtin_amdgcn_s_setprio(1);
#pragma unroll
  for (int dc = 0; dc < 4; ++dc) {
    const int rowb = (dc * 16 + lq) * 128;
    const bfx8 vf0 = *(const bfx8*)&vbuf[rowb + ((g * 16) ^ sw)];
    const bfx8 vf1 = *(const bfx8*)&vbuf[rowb + ((64 + g * 16) ^ sw)];
    A.acc[dc] =
        __builtin_amdgcn_mfma_f32_16x16x32_bf16(paA0, vf0, A.acc[dc], 0, 0, 0);
    A.acc[dc] =
        __builtin_amdgcn_mfma_f32_16x16x32_bf16(paA1, vf1, A.acc[dc], 0, 0, 0);
    if (doB) {
      B.acc[dc] = __builtin_amdgcn_mfma_f32_16x16x32_bf16(paB0, vf0, B.acc[dc],
                                                          0, 0, 0);
      B.acc[dc] = __builtin_amdgcn_mfma_f32_16x16x32_bf16(paB1, vf1, B.acc[dc],
                                                          0, 0, 0);
    }
  }
  __builtin_amdgcn_s_setprio(0);
}

__global__ __launch_bounds__(256, 2) void attn(
    const short* __restrict__ Q, const short* __restrict__ K,
    const short* __restrict__ VT, const unsigned short* __restrict__ pm,
    short* __restrict__ Y) {
  __shared__ char kv[2][16384];     // per buf: K tile 8KB | V^T tile 8KB
  __shared__ short P[4][16 * 72];   // per-wave P round-trip (hi)
  __shared__ short P2[4][16 * 72];  // per-wave P round-trip (lo)
  const int tid = threadIdx.x;
  const int w = tid >> 6, lane = tid & 63;
  const int lq = lane & 15, g = lane >> 4;
  const int bh = blockIdx.y, b = bh >> 4, h = bh & 15;
  const int tlo = blockIdx.x, thi = 31 - tlo;  // paired q-tiles
  const short* Qb = Q + (size_t)bh * TSEQ * DHEAD;
  const short* Kb = K + (size_t)bh * TSEQ * DHEAD;
  const short* Vb = VT + (size_t)bh * DHEAD * TSEQ;

  QPhase lo, hi;
  {
    const int qlo = tlo * 64 + w * 16 + lq;
    const int qhi = thi * 64 + w * 16 + lq;
    lo.qf0 = *(const bfx8*)(Qb + (size_t)qlo * DHEAD + g * 8);
    lo.qf1 = *(const bfx8*)(Qb + (size_t)qlo * DHEAD + 32 + g * 8);
    hi.qf0 = *(const bfx8*)(Qb + (size_t)qhi * DHEAD + g * 8);
    hi.qf1 = *(const bfx8*)(Qb + (size_t)qhi * DHEAD + 32 + g * 8);
#pragma unroll
    for (int dc = 0; dc < 4; ++dc) { lo.acc[dc] = f32x4{}; hi.acc[dc] = f32x4{}; }
    lo.m = -1e30f; lo.l = 0.f; hi.m = -1e30f; hi.l = 0.f;
    lo.pmr = pm + ((size_t)(b * TSEQ + qlo) << 7) + g;
    hi.pmr = pm + ((size_t)(b * TSEQ + qhi) << 7) + g;
  }

  const int sl = lane >> 3, sc = lane & 7;  // staging slot: row / col16
  const int ssw = (sc ^ sl) * 8;            // pre-swizzled source col (shorts)
  const int sw = (lq & 7) << 4;             // read-side XOR (bytes)

#define STAGE(bufn, k0s)                                                      \
  {                                                                           \
    _Pragma("unroll") for (int i = 0; i < 2; ++i) {                           \
      const int rr = w * 16 + i * 8;                                          \
      gload16(Kb + (size_t)((k0s) + rr + sl) * DHEAD + ssw,                   \
              &kv[bufn][rr * 128]);                                           \
      gload16(Vb + (size_t)(rr + sl) * TSEQ + (k0s) + ssw,                    \
              &kv[bufn][8192 + rr * 128]);                                    \
    }                                                                         \
  }

  STAGE(0, 0);
  __syncthreads();

  for (int t = 0; t <= thi; ++t) {
    const int buf = t & 1;
    if (t < thi) STAGE(buf ^ 1, (t + 1) * 64);
    attn_tile2(hi, lo, t <= tlo, kv[buf], kv[buf] + 8192, P[w], P2[w], t, sw,
               lq, g);
    __syncthreads();
  }

#pragma unroll
  for (int ph = 0; ph < 2; ++ph) {
    QPhase& S = ph ? hi : lo;
    const int q0 = (ph ? thi : tlo) * 64 + w * 16;
    float lr = S.l;  // per-lane partials -> row sum
    lr += __shfl_xor(lr, 16);
    lr += __shfl_xor(lr, 32);
    float li[4];
#pragma unroll
    for (int r = 0; r < 4; ++r) {
      const float lv = __shfl(lr, g * 4 + r);
      li[r] = lv > 0.f ? 1.f / lv : 0.f;
    }
#pragma unroll
    for (int dc = 0; dc < 4; ++dc)
#pragma unroll
      for (int r = 0; r < 4; ++r) {
        const int t = q0 + g * 4 + r;
        Y[((size_t)b * TSEQ + t) * CDIM + h * DHEAD + dc * 16 + lq] =
            (short)f2bf(S.acc[dc][r] * li[r]);
      }
  }
#undef STAGE
}

extern "C" void kernel_launch(void* const* d_in, const int* in_sizes, int n_in,
                              void* d_out, int out_size, void* d_ws,
                              size_t ws_size, hipStream_t stream) {
  const float* x = (const float*)d_in[0];
  const unsigned char* dyn = (const unsigned char*)d_in[1];
  const unsigned char* causal = (const unsigned char*)d_in[2];
  const float* Wq = (const float*)d_in[3];
  const float* bq = (const float*)d_in[4];
  const float* Wk = (const float*)d_in[5];
  const float* bk = (const float*)d_in[6];
  const float* Wv = (const float*)d_in[7];
  const float* bv = (const float*)d_in[8];
  const float* Wo = (const float*)d_in[9];
  const float* bo = (const float*)d_in[10];

  char* ws = (char*)d_ws;
  const size_t MB8 = 8ull * 1024 * 1024;
  short* xb = (short*)(ws + 0 * MB8);
  short* wall = (short*)(ws + 1 * MB8);  // Wq,Wk,Wv,Wo bf16 concatenated
  short* Qb = (short*)(ws + 2 * MB8);
  short* Kb = (short*)(ws + 3 * MB8);
  short* Vb = (short*)(ws + 4 * MB8);
  short* VTb = (short*)(ws + 5 * MB8);
  short* Yb = (short*)(ws + 6 * MB8);
  unsigned long long* pmask = (unsigned long long*)(ws + 7 * MB8);  // 1 MB

  convert_all<<<dim3(4096, 5), 256, 0, stream>>>(x, Wq, Wk, Wv, Wo, xb, wall);
  maskpack<<<dim3(32768), 256, 0, stream>>>(dyn, causal, pmask);
  gemm_nt<0><<<dim3(32, 8, 3), 256, 0, stream>>>(xb, wall, bq, bk, bv, Qb, Kb,
                                                 Vb, nullptr);
  vtrans<<<dim3(32, 32), 256, 0, stream>>>(Vb, VTb);
  attn<<<dim3(16, 32), 256, 0, stream>>>(Qb, Kb, VTb,
                                         (const unsigned short*)pmask, Yb);
  gemm_nt<1><<<dim3(32, 8, 1), 256, 0, stream>>>(Yb, wall, bo, nullptr, nullptr,
                                                 nullptr, nullptr, nullptr,
                                                 (float*)d_out);
}

// Round 9
// 137.872 us; speedup vs baseline: 1.2332x; 1.1118x over previous
//
#include <hip/hip_runtime.h>

#define TSEQ 2048
#define NHEAD 16
#define DHEAD 64
#define CDIM 1024
#define BATCH 2

typedef __attribute__((ext_vector_type(8))) short bfx8;
typedef __attribute__((ext_vector_type(4))) short bfx4;
typedef __attribute__((ext_vector_type(4))) float f32x4;

__device__ __forceinline__ unsigned short f2bf(float f) {
  unsigned u = __builtin_bit_cast(unsigned, f);
  u += 0x7fffu + ((u >> 16) & 1u);
  return (unsigned short)(u >> 16);
}

__device__ __forceinline__ unsigned cvtpk(float lo, float hi) {
  unsigned r;
  asm("v_cvt_pk_bf16_f32 %0, %1, %2" : "=v"(r) : "v"(lo), "v"(hi));
  return r;
}

__device__ __forceinline__ float max3f(float a, float b, float c) {
  float d;
  asm("v_max3_f32 %0, %1, %2, %3" : "=v"(d) : "v"(a), "v"(b), "v"(c));
  return d;
}

__device__ __forceinline__ void gload16(const void* g, void* l) {
  __builtin_amdgcn_global_load_lds(
      (const __attribute__((address_space(1))) unsigned*)g,
      (__attribute__((address_space(3))) unsigned*)l, 16, 0, 0);
}

// ---------------- elementwise fp32 -> bf16 conversion (x + 4 weights) -------
__global__ __launch_bounds__(256) void convert_all(
    const float* __restrict__ x,
    const float* __restrict__ wq, const float* __restrict__ wk,
    const float* __restrict__ wv, const float* __restrict__ wo,
    short* __restrict__ xb, short* __restrict__ wall) {
  const int y = blockIdx.y;
  const float* src;
  short* dst;
  int n;
  if (y == 0) { src = x; dst = xb; n = (BATCH * TSEQ * CDIM) / 4; }
  else {
    src = (y == 1) ? wq : (y == 2) ? wk : (y == 3) ? wv : wo;
    dst = wall + (size_t)(y - 1) * CDIM * CDIM;
    n = (CDIM * CDIM) / 4;
  }
  const int i = blockIdx.x * 256 + threadIdx.x;
  if (i < n) {
    const float4 v = ((const float4*)src)[i];
    bfx4 o;
    o[0] = (short)f2bf(v.x); o[1] = (short)f2bf(v.y);
    o[2] = (short)f2bf(v.z); o[3] = (short)f2bf(v.w);
    ((bfx4*)dst)[i] = o;
  }
}

// ---------------- combined mask pre-pack (ballot, 1 wave per u64) -----------
__global__ __launch_bounds__(256) void maskpack(
    const unsigned char* __restrict__ dyn,
    const unsigned char* __restrict__ causal,
    unsigned long long* __restrict__ pm) {
  const bool mbyte = (causal[32] != 0);  // dyn dtype probe (bool-as-byte?)
  const int wave = threadIdx.x >> 6, lane = threadIdx.x & 63;
  const int gid = blockIdx.x * 4 + wave;
  const int tile = gid & 31;
  const int q = (gid >> 5) & (TSEQ - 1);
  const int b = gid >> 16;
  const int g = lane >> 4, blk = (lane >> 2) & 3, r = lane & 3;
  const int k = tile * 64 + blk * 16 + g * 4 + r;
  const size_t off = ((size_t)b * TSEQ + q) * TSEQ + k;
  const bool dm = mbyte ? (dyn[off] != 0) : (((const int*)dyn)[off] != 0);
  const bool qok = (q & 3) != 3;
  const bool al =
      (((k >> 5) == (q >> 5)) || ((k <= q) && qok && (r != 3))) && !dm;
  const unsigned long long bal = __ballot(!al);
  if (lane == 0) pm[gid] = bal;
}

// ---------------- NT GEMM, 128x128 tile, dbuf prefetch ----------------------
// MODE 0: QKV -> bf16 scattered (b,h,t,d) via LDS-transposed coalesced
// epilogue (16B stores, FULL 2048-store cover); Q pre-scaled by 0.125*log2e.
// MODE 1: fp32 + bias.
template <int MODE>
__global__ __launch_bounds__(256) void gemm_nt(
    const short* __restrict__ A, const short* __restrict__ Ball,
    const float* __restrict__ bias0, const float* __restrict__ bias1,
    const float* __restrict__ bias2,
    short* __restrict__ Oq, short* __restrict__ Ok, short* __restrict__ Ov,
    float* __restrict__ Of) {
  __shared__ char arena[34816];  // As[2](16KB) Bs[2](16KB) | epi tile 34KB
  const int tid = threadIdx.x;
  const int w = tid >> 6, lane = tid & 63;
  const int lq = lane & 15, g = lane >> 4;
  const int wr = w >> 1, wc = w & 1;
  const int m0 = blockIdx.x * 128, n0 = blockIdx.y * 128;
  const int which = (MODE == 0) ? (int)blockIdx.z : 3;
  const short* B = Ball + (size_t)which * CDIM * CDIM;
#define ASB(bi) ((short*)(arena + (bi) * 8192))
#define BSB(bi) ((short*)(arena + 16384 + (bi) * 8192))
#define GS(bi, kt)                                                             \
  {                                                                            \
    _Pragma("unroll") for (int ph = 0; ph < 2; ++ph) {                         \
      const int c = ph * 256 + tid;                                            \
      gload16(A + (size_t)(m0 + (c >> 2)) * CDIM + (kt) * 32 + (c & 3) * 8,    \
              ASB(bi) + (ph * 256 + w * 64) * 8);                              \
      gload16(B + (size_t)(n0 + (c >> 2)) * CDIM + (kt) * 32 + (c & 3) * 8,    \
              BSB(bi) + (ph * 256 + w * 64) * 8);                              \
    }                                                                          \
  }
  GS(0, 0);
  __syncthreads();
  f32x4 acc[4][4] = {};
  for (int kt = 0; kt < CDIM / 32; ++kt) {
    const int bi = kt & 1;
    if (kt + 1 < CDIM / 32) GS(bi ^ 1, kt + 1);
    bfx8 af[4], bfr[4];
#pragma unroll
    for (int i = 0; i < 4; ++i)
      af[i] = *(const bfx8*)&ASB(bi)[(wr * 64 + i * 16 + lq) * 32 + g * 8];
#pragma unroll
    for (int i = 0; i < 4; ++i)
      bfr[i] = *(const bfx8*)&BSB(bi)[(wc * 64 + i * 16 + lq) * 32 + g * 8];
#pragma unroll
    for (int i = 0; i < 4; ++i)
#pragma unroll
      for (int j = 0; j < 4; ++j)
        acc[i][j] = __builtin_amdgcn_mfma_f32_16x16x32_bf16(af[i], bfr[j],
                                                            acc[i][j], 0, 0, 0);
    __syncthreads();
  }
#undef GS
  if (MODE == 0) {
    const float* bias = (which == 0) ? bias0 : (which == 1) ? bias1 : bias2;
    const float scale = (which == 0) ? 0.18033688011112042f : 1.0f;
    short* O = (which == 0) ? Oq : (which == 1) ? Ok : Ov;
    short* tile = (short*)arena;  // [128][136]
#pragma unroll
    for (int i = 0; i < 4; ++i)
#pragma unroll
      for (int j = 0; j < 4; ++j) {
        const int col = wc * 64 + j * 16 + lq;
        const float bb = bias[n0 + col];
#pragma unroll
        for (int r = 0; r < 4; ++r) {
          const int row = wr * 64 + i * 16 + g * 4 + r;
          tile[row * 136 + col] = (short)f2bf((acc[i][j][r] + bb) * scale);
        }
      }
    __syncthreads();
#pragma unroll
    for (int it = 0; it < 8; ++it) {
      const int id = it * 256 + tid;            // 2048 stores = full tile
      const int m = id >> 4, c16 = id & 15;
      const int row = m0 + m;
      const int b_ = row >> 11, t = row & (TSEQ - 1);
      const int h = (n0 >> 6) + (c16 >> 3), d0 = (c16 & 7) * 8;
      *(bfx8*)&O[(((size_t)b_ * NHEAD + h) * TSEQ + t) * DHEAD + d0] =
          *(const bfx8*)&tile[m * 136 + c16 * 8];
    }
  } else {
    const float* bias = bias0;
#pragma unroll
    for (int i = 0; i < 4; ++i)
#pragma unroll
      for (int j = 0; j < 4; ++j) {
        const int col = n0 + wc * 64 + j * 16 + lq;
        const float bb = bias[col];
#pragma unroll
        for (int r = 0; r < 4; ++r) {
          const int row = m0 + wr * 64 + i * 16 + g * 4 + r;
          Of[(size_t)row * CDIM + col] = acc[i][j][r] + bb;
        }
      }
  }
}

// ---------------- V (b,h,t,d) -> VT (b,h,d,t) -------------------------------
__global__ __launch_bounds__(256) void vtrans(const short* __restrict__ V,
                                              short* __restrict__ VT) {
  __shared__ short tile[64][72];
  const int bh = blockIdx.y;
  const int t0 = blockIdx.x * 64;
  const int tid = threadIdx.x;
  const short* src = V + ((size_t)bh * TSEQ + t0) * DHEAD;
#pragma unroll
  for (int ph = 0; ph < 4; ++ph) {
    const int c = ph * 256 + tid;
    const int row = c >> 4, col = (c & 15) * 4;
    *(bfx4*)&tile[row][col] = *(const bfx4*)(src + row * DHEAD + col);
  }
  __syncthreads();
  short* dst = VT + (size_t)bh * DHEAD * TSEQ + t0;
#pragma unroll
  for (int ph = 0; ph < 4; ++ph) {
    const int c = ph * 256 + tid;
    const int d = c >> 4, tc = (c & 15) * 4;
    bfx4 o;
    o[0] = tile[tc][d]; o[1] = tile[tc + 1][d];
    o[2] = tile[tc + 2][d]; o[3] = tile[tc + 3][d];
    *(bfx4*)(dst + (size_t)d * TSEQ + tc) = o;
  }
}

// ---------------- fused flash attention v7b ---------------------------------
// 8-wave blocks: waves 0-3 (group 0) handle k in [0,32), waves 4-7 k in
// [32,64) of every shared 64-k tile. STAGE uses a WAVE-UNIFORM LDS dest
// (w*1024; lane covers row w*8+lane/8, col (lane&7)*16) with per-lane
// swizzled global source -- the layout verified in v2-v6. Partial
// online-softmax states merged exactly in LDS at the end; group 0 stores Y.
struct QPhase {
  bfx8 qf0, qf1;
  f32x4 acc[4];
  float m, l;
  const unsigned short* pmr;  // packed-mask base for (b,q,g)
};

__device__ __forceinline__ void attn_half(QPhase& S, const char* kbuf,
                                          const char* vbuf, short* Pw, int t,
                                          int hf, int sw, int lq, int g) {
  const unsigned mb = (S.pmr[t << 2] >> (hf * 8)) & 0xffu;  // bit set=>masked
  f32x4 st[2] = {};
  __builtin_amdgcn_s_setprio(1);
#pragma unroll
  for (int b2 = 0; b2 < 2; ++b2) {
    const int rowb = ((hf * 2 + b2) * 16 + lq) * 128;
    const bfx8 kf0 = *(const bfx8*)&kbuf[rowb + ((g * 16) ^ sw)];
    const bfx8 kf1 = *(const bfx8*)&kbuf[rowb + ((64 + g * 16) ^ sw)];
    st[b2] =
        __builtin_amdgcn_mfma_f32_16x16x32_bf16(kf0, S.qf0, st[b2], 0, 0, 0);
    st[b2] =
        __builtin_amdgcn_mfma_f32_16x16x32_bf16(kf1, S.qf1, st[b2], 0, 0, 0);
  }
  __builtin_amdgcn_s_setprio(0);
  float s8[8];
#pragma unroll
  for (int idx = 0; idx < 8; ++idx)
    s8[idx] = ((mb >> idx) & 1u) ? -3.0e38f : st[idx >> 2][idx & 3];
  const float t0 = max3f(s8[0], s8[1], s8[2]);
  const float t1 = max3f(s8[3], s8[4], s8[5]);
  const float pmax = max3f(t0, t1, fmaxf(s8[6], s8[7]));
  if (!__all(pmax - S.m <= 8.f)) {  // rare slow path
    float smax = fmaxf(pmax, __shfl_xor(pmax, 16));
    smax = fmaxf(smax, __shfl_xor(smax, 32));
    const float mnew = fmaxf(S.m, smax);
    const float fac = __builtin_amdgcn_exp2f(S.m - mnew);
    S.l *= fac;
    float fr[4];
#pragma unroll
    for (int r = 0; r < 4; ++r) fr[r] = __shfl(fac, g * 4 + r);
#pragma unroll
    for (int dc = 0; dc < 4; ++dc) {
      S.acc[dc][0] *= fr[0]; S.acc[dc][1] *= fr[1];
      S.acc[dc][2] *= fr[2]; S.acc[dc][3] *= fr[3];
    }
    S.m = mnew;
  }
  float psum = 0.f;
#pragma unroll
  for (int idx = 0; idx < 8; ++idx) {
    const float e = __builtin_amdgcn_exp2f(s8[idx] - S.m);  // masked -> +0
    s8[idx] = e;
    psum += e;
  }
  S.l += psum;  // per-lane partial
  // P round-trip (k_local = b2*16 + g*4 + r within the 32-wide half)
#pragma unroll
  for (int b2 = 0; b2 < 2; ++b2) {
    uint2 u;
    u.x = cvtpk(s8[b2 * 4 + 0], s8[b2 * 4 + 1]);
    u.y = cvtpk(s8[b2 * 4 + 2], s8[b2 * 4 + 3]);
    *(uint2*)&Pw[lq * 40 + b2 * 16 + g * 4] = u;
  }
  __builtin_amdgcn_wave_barrier();
  const bfx8 pa = *(const bfx8*)&Pw[lq * 40 + g * 8];
  __builtin_amdgcn_wave_barrier();
  __builtin_amdgcn_s_setprio(1);
#pragma unroll
  for (int dc = 0; dc < 4; ++dc) {
    const bfx8 vf = *(const bfx8*)&vbuf[(dc * 16 + lq) * 128 +
                                        ((hf * 64 + g * 16) ^ sw)];
    S.acc[dc] =
        __builtin_amdgcn_mfma_f32_16x16x32_bf16(pa, vf, S.acc[dc], 0, 0, 0);
  }
  __builtin_amdgcn_s_setprio(0);
}

__global__ __launch_bounds__(512, 4) void attn(
    const short* __restrict__ Q, const short* __restrict__ K,
    const short* __restrict__ VT, const unsigned short* __restrict__ pm,
    short* __restrict__ Y) {
  __shared__ char arena[53248];  // kv 2x16KB | P 10KB | P2 10KB (epi: reuse)
  const int tid = threadIdx.x;
  const int w = tid >> 6, lane = tid & 63;
  const int hf = w >> 2, ws = w & 3;
  const int lq = lane & 15, g = lane >> 4;
  const int bh = blockIdx.y, b = bh >> 4, h = bh & 15;
  const int tlo = blockIdx.x, thi = 31 - tlo;  // paired q-tiles
  const short* Qb = Q + (size_t)bh * TSEQ * DHEAD;
  const short* Kb = K + (size_t)bh * TSEQ * DHEAD;
  const short* Vb = VT + (size_t)bh * DHEAD * TSEQ;

  QPhase lo, hi;
  {
    const int qlo = tlo * 64 + ws * 16 + lq;
    const int qhi = thi * 64 + ws * 16 + lq;
    lo.qf0 = *(const bfx8*)(Qb + (size_t)qlo * DHEAD + g * 8);
    lo.qf1 = *(const bfx8*)(Qb + (size_t)qlo * DHEAD + 32 + g * 8);
    hi.qf0 = *(const bfx8*)(Qb + (size_t)qhi * DHEAD + g * 8);
    hi.qf1 = *(const bfx8*)(Qb + (size_t)qhi * DHEAD + 32 + g * 8);
#pragma unroll
    for (int dc = 0; dc < 4; ++dc) { lo.acc[dc] = f32x4{}; hi.acc[dc] = f32x4{}; }
    lo.m = -1e30f; lo.l = 0.f; hi.m = -1e30f; hi.l = 0.f;
    lo.pmr = pm + ((size_t)(b * TSEQ + qlo) << 7) + g;
    hi.pmr = pm + ((size_t)(b * TSEQ + qhi) << 7) + g;
  }

  const int sl = lane >> 3, sc = lane & 7;  // staging: row sub / col16
  const int ssw = (sc ^ sl) * 8;            // pre-swizzled source col (shorts)
  const int sw = (lq & 7) << 4;             // read-side XOR (bytes)
  short* Pw = (short*)(arena + 32768 + w * 1280);   // [16][40] per wave
  short* P2w = (short*)(arena + 43008 + w * 1280);  // second stream

  // Wave-uniform LDS dest (w*1024); per-lane swizzled global source.
#define STAGE(bufn, k0s)                                                      \
  {                                                                           \
    gload16(Kb + (size_t)((k0s) + w * 8 + sl) * DHEAD + ssw,                  \
            arena + (bufn) * 16384 + w * 1024);                               \
    gload16(Vb + (size_t)(w * 8 + sl) * TSEQ + (k0s) + ssw,                   \
            arena + (bufn) * 16384 + 8192 + w * 1024);                        \
  }

  STAGE(0, 0);
  __syncthreads();

  for (int t = 0; t <= thi; ++t) {
    const int buf = t & 1;
    if (t < thi) STAGE(buf ^ 1, (t + 1) * 64);
    const char* kbuf = arena + buf * 16384;
    const char* vbuf = kbuf + 8192;
    attn_half(hi, kbuf, vbuf, Pw, t, hf, sw, lq, g);
    if (t <= tlo) attn_half(lo, kbuf, vbuf, P2w, t, hf, sw, lq, g);
    __syncthreads();
  }
#undef STAGE

  // ---- merge the two k-half states (group1 -> LDS, group0 merges+stores)
  float* exA = (float*)arena;                    // 8 x 4KB acc
  float2* exM = (float2*)(arena + 32768);        // 8 x 512B (m,l)
  if (hf == 1) {
#pragma unroll
    for (int ph = 0; ph < 2; ++ph) {
      QPhase& S = ph ? hi : lo;
      float* a = exA + (ws * 2 + ph) * 1024;
#pragma unroll
      for (int dc = 0; dc < 4; ++dc)
        *(f32x4*)&a[lane * 16 + dc * 4] = S.acc[dc];
      exM[(ws * 2 + ph) * 64 + lane] = float2{S.m, S.l};
    }
  }
  __syncthreads();
  if (hf == 0) {
#pragma unroll
    for (int ph = 0; ph < 2; ++ph) {
      QPhase& S = ph ? hi : lo;
      const float* a = exA + (ws * 2 + ph) * 1024;
      const float2 mlB = exM[(ws * 2 + ph) * 64 + lane];
      const float ms = fmaxf(S.m, mlB.x);
      const float fA = __builtin_amdgcn_exp2f(S.m - ms);
      const float fB = __builtin_amdgcn_exp2f(mlB.x - ms);
      float lr = S.l * fA + mlB.y * fB;
      lr += __shfl_xor(lr, 16);
      lr += __shfl_xor(lr, 32);
      float frA[4], frB[4], li[4];
#pragma unroll
      for (int r = 0; r < 4; ++r) {
        frA[r] = __shfl(fA, g * 4 + r);
        frB[r] = __shfl(fB, g * 4 + r);
        const float lv = __shfl(lr, g * 4 + r);
        li[r] = lv > 0.f ? 1.f / lv : 0.f;
      }
      const int q0 = (ph ? thi : tlo) * 64 + ws * 16;
#pragma unroll
      for (int dc = 0; dc < 4; ++dc) {
        const f32x4 ab = *(const f32x4*)&a[lane * 16 + dc * 4];
#pragma unroll
        for (int r = 0; r < 4; ++r) {
          const int t = q0 + g * 4 + r;
          Y[((size_t)b * TSEQ + t) * CDIM + h * DHEAD + dc * 16 + lq] =
              (short)f2bf((S.acc[dc][r] * frA[r] + ab[r] * frB[r]) * li[r]);
        }
      }
    }
  }
}

extern "C" void kernel_launch(void* const* d_in, const int* in_sizes, int n_in,
                              void* d_out, int out_size, void* d_ws,
                              size_t ws_size, hipStream_t stream) {
  const float* x = (const float*)d_in[0];
  const unsigned char* dyn = (const unsigned char*)d_in[1];
  const unsigned char* causal = (const unsigned char*)d_in[2];
  const float* Wq = (const float*)d_in[3];
  const float* bq = (const float*)d_in[4];
  const float* Wk = (const float*)d_in[5];
  const float* bk = (const float*)d_in[6];
  const float* Wv = (const float*)d_in[7];
  const float* bv = (const float*)d_in[8];
  const float* Wo = (const float*)d_in[9];
  const float* bo = (const float*)d_in[10];

  char* ws = (char*)d_ws;
  const size_t MB8 = 8ull * 1024 * 1024;
  short* xb = (short*)(ws + 0 * MB8);
  short* wall = (short*)(ws + 1 * MB8);  // Wq,Wk,Wv,Wo bf16 concatenated
  short* Qb = (short*)(ws + 2 * MB8);
  short* Kb = (short*)(ws + 3 * MB8);
  short* Vb = (short*)(ws + 4 * MB8);
  short* VTb = (short*)(ws + 5 * MB8);
  short* Yb = (short*)(ws + 6 * MB8);
  unsigned long long* pmask = (unsigned long long*)(ws + 7 * MB8);  // 1 MB

  convert_all<<<dim3(4096, 5), 256, 0, stream>>>(x, Wq, Wk, Wv, Wo, xb, wall);
  maskpack<<<dim3(32768), 256, 0, stream>>>(dyn, causal, pmask);
  gemm_nt<0><<<dim3(32, 8, 3), 256, 0, stream>>>(xb, wall, bq, bk, bv, Qb, Kb,
                                                 Vb, nullptr);
  vtrans<<<dim3(32, 32), 256, 0, stream>>>(Vb, VTb);
  attn<<<dim3(16, 32), 512, 0, stream>>>(Qb, Kb, VTb,
                                         (const unsigned short*)pmask, Yb);
  gemm_nt<1><<<dim3(32, 8, 1), 256, 0, stream>>>(Yb, wall, bo, nullptr, nullptr,
                                                 nullptr, nullptr, nullptr,
                                                 (float*)d_out);
}

// Round 10
// 131.942 us; speedup vs baseline: 1.2886x; 1.0449x over previous
//
#include <hip/hip_runtime.h>

#define TSEQ 2048
#define NHEAD 16
#define DHEAD 64
#define CDIM 1024
#define BATCH 2

typedef __attribute__((ext_vector_type(8))) short bfx8;
typedef __attribute__((ext_vector_type(4))) short bfx4;
typedef __attribute__((ext_vector_type(4))) float f32x4;

__device__ __forceinline__ unsigned short f2bf(float f) {
  unsigned u = __builtin_bit_cast(unsigned, f);
  u += 0x7fffu + ((u >> 16) & 1u);
  return (unsigned short)(u >> 16);
}

__device__ __forceinline__ unsigned cvtpk(float lo, float hi) {
  unsigned r;
  asm("v_cvt_pk_bf16_f32 %0, %1, %2" : "=v"(r) : "v"(lo), "v"(hi));
  return r;
}

__device__ __forceinline__ float max3f(float a, float b, float c) {
  float d;
  asm("v_max3_f32 %0, %1, %2, %3" : "=v"(d) : "v"(a), "v"(b), "v"(c));
  return d;
}

__device__ __forceinline__ void gload16(const void* g, void* l) {
  __builtin_amdgcn_global_load_lds(
      (const __attribute__((address_space(1))) unsigned*)g,
      (__attribute__((address_space(3))) unsigned*)l, 16, 0, 0);
}

// ---------------- elementwise fp32 -> bf16 conversion (x + 4 weights) -------
__global__ __launch_bounds__(256) void convert_all(
    const float* __restrict__ x,
    const float* __restrict__ wq, const float* __restrict__ wk,
    const float* __restrict__ wv, const float* __restrict__ wo,
    short* __restrict__ xb, short* __restrict__ wall) {
  const int y = blockIdx.y;
  const float* src;
  short* dst;
  int n;
  if (y == 0) { src = x; dst = xb; n = (BATCH * TSEQ * CDIM) / 4; }
  else {
    src = (y == 1) ? wq : (y == 2) ? wk : (y == 3) ? wv : wo;
    dst = wall + (size_t)(y - 1) * CDIM * CDIM;
    n = (CDIM * CDIM) / 4;
  }
  const int i = blockIdx.x * 256 + threadIdx.x;
  if (i < n) {
    const float4 v = ((const float4*)src)[i];
    bfx4 o;
    o[0] = (short)f2bf(v.x); o[1] = (short)f2bf(v.y);
    o[2] = (short)f2bf(v.z); o[3] = (short)f2bf(v.w);
    ((bfx4*)dst)[i] = o;
  }
}

// ---------------- combined mask pre-pack (ballot, 1 wave per u64) -----------
__global__ __launch_bounds__(256) void maskpack(
    const unsigned char* __restrict__ dyn,
    const unsigned char* __restrict__ causal,
    unsigned long long* __restrict__ pm) {
  const bool mbyte = (causal[32] != 0);  // dyn dtype probe (bool-as-byte?)
  const int wave = threadIdx.x >> 6, lane = threadIdx.x & 63;
  const int gid = blockIdx.x * 4 + wave;
  const int tile = gid & 31;
  const int q = (gid >> 5) & (TSEQ - 1);
  const int b = gid >> 16;
  const int g = lane >> 4, blk = (lane >> 2) & 3, r = lane & 3;
  const int k = tile * 64 + blk * 16 + g * 4 + r;
  const size_t off = ((size_t)b * TSEQ + q) * TSEQ + k;
  const bool dm = mbyte ? (dyn[off] != 0) : (((const int*)dyn)[off] != 0);
  const bool qok = (q & 3) != 3;
  const bool al =
      (((k >> 5) == (q >> 5)) || ((k <= q) && qok && (r != 3))) && !dm;
  const unsigned long long bal = __ballot(!al);
  if (lane == 0) pm[gid] = bal;
}

// ---------------- QKV NT GEMM, 128x128 tile, dbuf prefetch ------------------
// z in {0,1,2} -> Q/K/V. Q,K: bf16 scattered (b,h,t,d) via LDS tile (stride
// 136, 16B coalesced stores); Q pre-scaled by 0.125*log2e. V (z==2): epilogue
// writes VT (b,h,d,t) DIRECTLY from the LDS tile (stride 137 -> ~2-way
// conflicts; 256B-contiguous stores along t) -- no separate vtrans pass.
__global__ __launch_bounds__(256) void gemm_qkv(
    const short* __restrict__ A, const short* __restrict__ Ball,
    const float* __restrict__ bias0, const float* __restrict__ bias1,
    const float* __restrict__ bias2,
    short* __restrict__ Oq, short* __restrict__ Ok, short* __restrict__ VT) {
  __shared__ char arena[35072];  // staging 32KB | epi tile 128x137x2B
  const int tid = threadIdx.x;
  const int w = tid >> 6, lane = tid & 63;
  const int lq = lane & 15, g = lane >> 4;
  const int wr = w >> 1, wc = w & 1;
  const int m0 = blockIdx.x * 128, n0 = blockIdx.y * 128;
  const int which = blockIdx.z;
  const short* B = Ball + (size_t)which * CDIM * CDIM;
#define ASB(bi) ((short*)(arena + (bi) * 8192))
#define BSB(bi) ((short*)(arena + 16384 + (bi) * 8192))
#define GS(bi, kt)                                                             \
  {                                                                            \
    _Pragma("unroll") for (int ph = 0; ph < 2; ++ph) {                         \
      const int c = ph * 256 + tid;                                            \
      gload16(A + (size_t)(m0 + (c >> 2)) * CDIM + (kt) * 32 + (c & 3) * 8,    \
              ASB(bi) + (ph * 256 + w * 64) * 8);                              \
      gload16(B + (size_t)(n0 + (c >> 2)) * CDIM + (kt) * 32 + (c & 3) * 8,    \
              BSB(bi) + (ph * 256 + w * 64) * 8);                              \
    }                                                                          \
  }
  GS(0, 0);
  __syncthreads();
  f32x4 acc[4][4] = {};
  for (int kt = 0; kt < CDIM / 32; ++kt) {
    const int bi = kt & 1;
    if (kt + 1 < CDIM / 32) GS(bi ^ 1, kt + 1);
    bfx8 af[4], bfr[4];
#pragma unroll
    for (int i = 0; i < 4; ++i)
      af[i] = *(const bfx8*)&ASB(bi)[(wr * 64 + i * 16 + lq) * 32 + g * 8];
#pragma unroll
    for (int i = 0; i < 4; ++i)
      bfr[i] = *(const bfx8*)&BSB(bi)[(wc * 64 + i * 16 + lq) * 32 + g * 8];
#pragma unroll
    for (int i = 0; i < 4; ++i)
#pragma unroll
      for (int j = 0; j < 4; ++j)
        acc[i][j] = __builtin_amdgcn_mfma_f32_16x16x32_bf16(af[i], bfr[j],
                                                            acc[i][j], 0, 0, 0);
    __syncthreads();
  }
#undef GS
  const float* bias = (which == 0) ? bias0 : (which == 1) ? bias1 : bias2;
  const float scale = (which == 0) ? 0.18033688011112042f : 1.0f;
  short* tile = (short*)arena;
  const int rs = (which == 2) ? 137 : 136;  // V path: odd stride for T-reads
#pragma unroll
  for (int i = 0; i < 4; ++i)
#pragma unroll
    for (int j = 0; j < 4; ++j) {
      const int col = wc * 64 + j * 16 + lq;
      const float bb = bias[n0 + col];
#pragma unroll
      for (int r = 0; r < 4; ++r) {
        const int row = wr * 64 + i * 16 + g * 4 + r;
        tile[row * rs + col] = (short)f2bf((acc[i][j][r] + bb) * scale);
      }
    }
  __syncthreads();
  const int b_ = m0 >> 11, t0 = m0 & (TSEQ - 1);
  if (which == 2) {
    // VT[(b,h,d)][t]: thread covers (d128 = id>>4, tseg = id&15), 8 t's each
#pragma unroll
    for (int it = 0; it < 8; ++it) {
      const int id = it * 256 + tid;
      const int tseg = id & 15, d128 = id >> 4;
      const int h = (n0 >> 6) + (d128 >> 6), d = d128 & 63;
      bfx8 o;
#pragma unroll
      for (int j = 0; j < 8; ++j) o[j] = tile[(tseg * 8 + j) * 137 + d128];
      *(bfx8*)&VT[(((size_t)b_ * NHEAD + h) * DHEAD + d) * TSEQ + t0 +
                  tseg * 8] = o;
    }
  } else {
    short* O = (which == 0) ? Oq : Ok;
#pragma unroll
    for (int it = 0; it < 8; ++it) {
      const int id = it * 256 + tid;  // 2048 stores = full tile
      const int m = id >> 4, c16 = id & 15;
      const int h = (n0 >> 6) + (c16 >> 3), d0 = (c16 & 7) * 8;
      *(bfx8*)&O[(((size_t)b_ * NHEAD + h) * TSEQ + t0 + m) * DHEAD + d0] =
          *(const bfx8*)&tile[m * 136 + c16 * 8];
    }
  }
}

// ---------------- output projection NT GEMM, 64x128 tile --------------------
// grid (64,8) = 512 blocks -> 2 blocks/CU (the 128x128 version ran at exactly
// 1 block/CU: zero latency hiding). fp32 out + bias.
__global__ __launch_bounds__(256) void gemm_out(
    const short* __restrict__ A, const short* __restrict__ B,
    const float* __restrict__ bias, float* __restrict__ Of) {
  __shared__ char arena[24576];  // As 2x4KB | Bs 2x8KB
  const int tid = threadIdx.x;
  const int w = tid >> 6, lane = tid & 63;
  const int lq = lane & 15, g = lane >> 4;
  const int wr = w >> 1, wc = w & 1;
  const int m0 = blockIdx.x * 64, n0 = blockIdx.y * 128;
#define ASB(bi) ((short*)(arena + (bi) * 4096))
#define BSB(bi) ((short*)(arena + 8192 + (bi) * 8192))
#define GS(bi, kt)                                                             \
  {                                                                            \
    gload16(A + (size_t)(m0 + (tid >> 2)) * CDIM + (kt) * 32 + (tid & 3) * 8,  \
            ASB(bi) + (w * 64) * 8);                                           \
    _Pragma("unroll") for (int ph = 0; ph < 2; ++ph) {                         \
      const int c = ph * 256 + tid;                                            \
      gload16(B + (size_t)(n0 + (c >> 2)) * CDIM + (kt) * 32 + (c & 3) * 8,    \
              BSB(bi) + (ph * 256 + w * 64) * 8);                              \
    }                                                                          \
  }
  GS(0, 0);
  __syncthreads();
  f32x4 acc[2][4] = {};
  for (int kt = 0; kt < CDIM / 32; ++kt) {
    const int bi = kt & 1;
    if (kt + 1 < CDIM / 32) GS(bi ^ 1, kt + 1);
    bfx8 af[2], bfr[4];
#pragma unroll
    for (int i = 0; i < 2; ++i)
      af[i] = *(const bfx8*)&ASB(bi)[(wr * 32 + i * 16 + lq) * 32 + g * 8];
#pragma unroll
    for (int j = 0; j < 4; ++j)
      bfr[j] = *(const bfx8*)&BSB(bi)[(wc * 64 + j * 16 + lq) * 32 + g * 8];
#pragma unroll
    for (int i = 0; i < 2; ++i)
#pragma unroll
      for (int j = 0; j < 4; ++j)
        acc[i][j] = __builtin_amdgcn_mfma_f32_16x16x32_bf16(af[i], bfr[j],
                                                            acc[i][j], 0, 0, 0);
    __syncthreads();
  }
#undef GS
#undef ASB
#undef BSB
#pragma unroll
  for (int i = 0; i < 2; ++i)
#pragma unroll
    for (int j = 0; j < 4; ++j) {
      const int col = n0 + wc * 64 + j * 16 + lq;
      const float bb = bias[col];
#pragma unroll
      for (int r = 0; r < 4; ++r) {
        const int row = m0 + wr * 32 + i * 16 + g * 4 + r;
        Of[(size_t)row * CDIM + col] = acc[i][j][r] + bb;
      }
    }
}

// ---------------- fused flash attention v8 ----------------------------------
// v7b + single shared P buffer for both q-streams (in-wave serialized by
// wave_barrier) -> LDS 43KB.
struct QPhase {
  bfx8 qf0, qf1;
  f32x4 acc[4];
  float m, l;
  const unsigned short* pmr;  // packed-mask base for (b,q,g)
};

__device__ __forceinline__ void attn_half(QPhase& S, const char* kbuf,
                                          const char* vbuf, short* Pw, int t,
                                          int hf, int sw, int lq, int g) {
  const unsigned mb = (S.pmr[t << 2] >> (hf * 8)) & 0xffu;  // bit set=>masked
  f32x4 st[2] = {};
  __builtin_amdgcn_s_setprio(1);
#pragma unroll
  for (int b2 = 0; b2 < 2; ++b2) {
    const int rowb = ((hf * 2 + b2) * 16 + lq) * 128;
    const bfx8 kf0 = *(const bfx8*)&kbuf[rowb + ((g * 16) ^ sw)];
    const bfx8 kf1 = *(const bfx8*)&kbuf[rowb + ((64 + g * 16) ^ sw)];
    st[b2] =
        __builtin_amdgcn_mfma_f32_16x16x32_bf16(kf0, S.qf0, st[b2], 0, 0, 0);
    st[b2] =
        __builtin_amdgcn_mfma_f32_16x16x32_bf16(kf1, S.qf1, st[b2], 0, 0, 0);
  }
  __builtin_amdgcn_s_setprio(0);
  float s8[8];
#pragma unroll
  for (int idx = 0; idx < 8; ++idx)
    s8[idx] = ((mb >> idx) & 1u) ? -3.0e38f : st[idx >> 2][idx & 3];
  const float t0 = max3f(s8[0], s8[1], s8[2]);
  const float t1 = max3f(s8[3], s8[4], s8[5]);
  const float pmax = max3f(t0, t1, fmaxf(s8[6], s8[7]));
  if (!__all(pmax - S.m <= 8.f)) {  // rare slow path
    float smax = fmaxf(pmax, __shfl_xor(pmax, 16));
    smax = fmaxf(smax, __shfl_xor(smax, 32));
    const float mnew = fmaxf(S.m, smax);
    const float fac = __builtin_amdgcn_exp2f(S.m - mnew);
    S.l *= fac;
    float fr[4];
#pragma unroll
    for (int r = 0; r < 4; ++r) fr[r] = __shfl(fac, g * 4 + r);
#pragma unroll
    for (int dc = 0; dc < 4; ++dc) {
      S.acc[dc][0] *= fr[0]; S.acc[dc][1] *= fr[1];
      S.acc[dc][2] *= fr[2]; S.acc[dc][3] *= fr[3];
    }
    S.m = mnew;
  }
  float psum = 0.f;
#pragma unroll
  for (int idx = 0; idx < 8; ++idx) {
    const float e = __builtin_amdgcn_exp2f(s8[idx] - S.m);  // masked -> +0
    s8[idx] = e;
    psum += e;
  }
  S.l += psum;  // per-lane partial
  // P round-trip (k_local = b2*16 + g*4 + r within the 32-wide half)
#pragma unroll
  for (int b2 = 0; b2 < 2; ++b2) {
    uint2 u;
    u.x = cvtpk(s8[b2 * 4 + 0], s8[b2 * 4 + 1]);
    u.y = cvtpk(s8[b2 * 4 + 2], s8[b2 * 4 + 3]);
    *(uint2*)&Pw[lq * 40 + b2 * 16 + g * 4] = u;
  }
  __builtin_amdgcn_wave_barrier();
  const bfx8 pa = *(const bfx8*)&Pw[lq * 40 + g * 8];
  __builtin_amdgcn_wave_barrier();
  __builtin_amdgcn_s_setprio(1);
#pragma unroll
  for (int dc = 0; dc < 4; ++dc) {
    const bfx8 vf = *(const bfx8*)&vbuf[(dc * 16 + lq) * 128 +
                                        ((hf * 64 + g * 16) ^ sw)];
    S.acc[dc] =
        __builtin_amdgcn_mfma_f32_16x16x32_bf16(pa, vf, S.acc[dc], 0, 0, 0);
  }
  __builtin_amdgcn_s_setprio(0);
}

__global__ __launch_bounds__(512, 4) void attn(
    const short* __restrict__ Q, const short* __restrict__ K,
    const short* __restrict__ VT, const unsigned short* __restrict__ pm,
    short* __restrict__ Y) {
  __shared__ char arena[43008];  // kv 2x16KB | P 10KB (epi: reuse)
  const int tid = threadIdx.x;
  const int w = tid >> 6, lane = tid & 63;
  const int hf = w >> 2, ws = w & 3;
  const int lq = lane & 15, g = lane >> 4;
  const int bh = blockIdx.y, b = bh >> 4, h = bh & 15;
  const int tlo = blockIdx.x, thi = 31 - tlo;  // paired q-tiles
  const short* Qb = Q + (size_t)bh * TSEQ * DHEAD;
  const short* Kb = K + (size_t)bh * TSEQ * DHEAD;
  const short* Vb = VT + (size_t)bh * DHEAD * TSEQ;

  QPhase lo, hi;
  {
    const int qlo = tlo * 64 + ws * 16 + lq;
    const int qhi = thi * 64 + ws * 16 + lq;
    lo.qf0 = *(const bfx8*)(Qb + (size_t)qlo * DHEAD + g * 8);
    lo.qf1 = *(const bfx8*)(Qb + (size_t)qlo * DHEAD + 32 + g * 8);
    hi.qf0 = *(const bfx8*)(Qb + (size_t)qhi * DHEAD + g * 8);
    hi.qf1 = *(const bfx8*)(Qb + (size_t)qhi * DHEAD + 32 + g * 8);
#pragma unroll
    for (int dc = 0; dc < 4; ++dc) { lo.acc[dc] = f32x4{}; hi.acc[dc] = f32x4{}; }
    lo.m = -1e30f; lo.l = 0.f; hi.m = -1e30f; hi.l = 0.f;
    lo.pmr = pm + ((size_t)(b * TSEQ + qlo) << 7) + g;
    hi.pmr = pm + ((size_t)(b * TSEQ + qhi) << 7) + g;
  }

  const int sl = lane >> 3, sc = lane & 7;  // staging: row sub / col16
  const int ssw = (sc ^ sl) * 8;            // pre-swizzled source col (shorts)
  const int sw = (lq & 7) << 4;             // read-side XOR (bytes)
  short* Pw = (short*)(arena + 32768 + w * 1280);  // [16][40] per wave

  // Wave-uniform LDS dest (w*1024); per-lane swizzled global source.
#define STAGE(bufn, k0s)                                                      \
  {                                                                           \
    gload16(Kb + (size_t)((k0s) + w * 8 + sl) * DHEAD + ssw,                  \
            arena + (bufn) * 16384 + w * 1024);                               \
    gload16(Vb + (size_t)(w * 8 + sl) * TSEQ + (k0s) + ssw,                   \
            arena + (bufn) * 16384 + 8192 + w * 1024);                        \
  }

  STAGE(0, 0);
  __syncthreads();

  for (int t = 0; t <= thi; ++t) {
    const int buf = t & 1;
    if (t < thi) STAGE(buf ^ 1, (t + 1) * 64);
    const char* kbuf = arena + buf * 16384;
    const char* vbuf = kbuf + 8192;
    attn_half(hi, kbuf, vbuf, Pw, t, hf, sw, lq, g);
    if (t <= tlo) attn_half(lo, kbuf, vbuf, Pw, t, hf, sw, lq, g);
    __syncthreads();
  }
#undef STAGE

  // ---- merge the two k-half states (group1 -> LDS, group0 merges+stores)
  float* exA = (float*)arena;                    // 8 x 4KB acc
  float2* exM = (float2*)(arena + 32768);        // 8 x 512B (m,l)
  if (hf == 1) {
#pragma unroll
    for (int ph = 0; ph < 2; ++ph) {
      QPhase& S = ph ? hi : lo;
      float* a = exA + (ws * 2 + ph) * 1024;
#pragma unroll
      for (int dc = 0; dc < 4; ++dc)
        *(f32x4*)&a[lane * 16 + dc * 4] = S.acc[dc];
      exM[(ws * 2 + ph) * 64 + lane] = float2{S.m, S.l};
    }
  }
  __syncthreads();
  if (hf == 0) {
#pragma unroll
    for (int ph = 0; ph < 2; ++ph) {
      QPhase& S = ph ? hi : lo;
      const float* a = exA + (ws * 2 + ph) * 1024;
      const float2 mlB = exM[(ws * 2 + ph) * 64 + lane];
      const float ms = fmaxf(S.m, mlB.x);
      const float fA = __builtin_amdgcn_exp2f(S.m - ms);
      const float fB = __builtin_amdgcn_exp2f(mlB.x - ms);
      float lr = S.l * fA + mlB.y * fB;
      lr += __shfl_xor(lr, 16);
      lr += __shfl_xor(lr, 32);
      float frA[4], frB[4], li[4];
#pragma unroll
      for (int r = 0; r < 4; ++r) {
        frA[r] = __shfl(fA, g * 4 + r);
        frB[r] = __shfl(fB, g * 4 + r);
        const float lv = __shfl(lr, g * 4 + r);
        li[r] = lv > 0.f ? 1.f / lv : 0.f;
      }
      const int q0 = (ph ? thi : tlo) * 64 + ws * 16;
#pragma unroll
      for (int dc = 0; dc < 4; ++dc) {
        const f32x4 ab = *(const f32x4*)&a[lane * 16 + dc * 4];
#pragma unroll
        for (int r = 0; r < 4; ++r) {
          const int t = q0 + g * 4 + r;
          Y[((size_t)b * TSEQ + t) * CDIM + h * DHEAD + dc * 16 + lq] =
              (short)f2bf((S.acc[dc][r] * frA[r] + ab[r] * frB[r]) * li[r]);
        }
      }
    }
  }
}

extern "C" void kernel_launch(void* const* d_in, const int* in_sizes, int n_in,
                              void* d_out, int out_size, void* d_ws,
                              size_t ws_size, hipStream_t stream) {
  const float* x = (const float*)d_in[0];
  const unsigned char* dyn = (const unsigned char*)d_in[1];
  const unsigned char* causal = (const unsigned char*)d_in[2];
  const float* Wq = (const float*)d_in[3];
  const float* bq = (const float*)d_in[4];
  const float* Wk = (const float*)d_in[5];
  const float* bk = (const float*)d_in[6];
  const float* Wv = (const float*)d_in[7];
  const float* bv = (const float*)d_in[8];
  const float* Wo = (const float*)d_in[9];
  const float* bo = (const float*)d_in[10];

  char* ws = (char*)d_ws;
  const size_t MB8 = 8ull * 1024 * 1024;
  short* xb = (short*)(ws + 0 * MB8);
  short* wall = (short*)(ws + 1 * MB8);  // Wq,Wk,Wv,Wo bf16 concatenated
  short* Qb = (short*)(ws + 2 * MB8);
  short* Kb = (short*)(ws + 3 * MB8);
  short* VTb = (short*)(ws + 5 * MB8);
  short* Yb = (short*)(ws + 6 * MB8);
  unsigned long long* pmask = (unsigned long long*)(ws + 7 * MB8);  // 1 MB

  convert_all<<<dim3(4096, 5), 256, 0, stream>>>(x, Wq, Wk, Wv, Wo, xb, wall);
  maskpack<<<dim3(32768), 256, 0, stream>>>(dyn, causal, pmask);
  gemm_qkv<<<dim3(32, 8, 3), 256, 0, stream>>>(xb, wall, bq, bk, bv, Qb, Kb,
                                               VTb);
  attn<<<dim3(16, 32), 512, 0, stream>>>(Qb, Kb, VTb,
                                         (const unsigned short*)pmask, Yb);
  gemm_out<<<dim3(64, 8), 256, 0, stream>>>(Yb, wall + 3 * CDIM * CDIM, bo,
                                            (float*)d_out);
}

// Round 11
// 126.880 us; speedup vs baseline: 1.3400x; 1.0399x over previous
//
#include <hip/hip_runtime.h>

#define TSEQ 2048
#define NHEAD 16
#define DHEAD 64
#define CDIM 1024
#define BATCH 2

typedef __attribute__((ext_vector_type(8))) short bfx8;
typedef __attribute__((ext_vector_type(4))) short bfx4;
typedef __attribute__((ext_vector_type(4))) float f32x4;

__device__ __forceinline__ unsigned short f2bf(float f) {
  unsigned u = __builtin_bit_cast(unsigned, f);
  u += 0x7fffu + ((u >> 16) & 1u);
  return (unsigned short)(u >> 16);
}

__device__ __forceinline__ unsigned cvtpk(float lo, float hi) {
  unsigned r;
  asm("v_cvt_pk_bf16_f32 %0, %1, %2" : "=v"(r) : "v"(lo), "v"(hi));
  return r;
}

__device__ __forceinline__ float max3f(float a, float b, float c) {
  float d;
  asm("v_max3_f32 %0, %1, %2, %3" : "=v"(d) : "v"(a), "v"(b), "v"(c));
  return d;
}

__device__ __forceinline__ void gload16(const void* g, void* l) {
  __builtin_amdgcn_global_load_lds(
      (const __attribute__((address_space(1))) unsigned*)g,
      (__attribute__((address_space(3))) unsigned*)l, 16, 0, 0);
}

// ---------------- elementwise fp32 -> bf16 conversion (x + 4 weights) -------
__global__ __launch_bounds__(256) void convert_all(
    const float* __restrict__ x,
    const float* __restrict__ wq, const float* __restrict__ wk,
    const float* __restrict__ wv, const float* __restrict__ wo,
    short* __restrict__ xb, short* __restrict__ wall) {
  const int y = blockIdx.y;
  const float* src;
  short* dst;
  int n;
  if (y == 0) { src = x; dst = xb; n = (BATCH * TSEQ * CDIM) / 4; }
  else {
    src = (y == 1) ? wq : (y == 2) ? wk : (y == 3) ? wv : wo;
    dst = wall + (size_t)(y - 1) * CDIM * CDIM;
    n = (CDIM * CDIM) / 4;
  }
  const int i = blockIdx.x * 256 + threadIdx.x;
  if (i < n) {
    const float4 v = ((const float4*)src)[i];
    bfx4 o;
    o[0] = (short)f2bf(v.x); o[1] = (short)f2bf(v.y);
    o[2] = (short)f2bf(v.z); o[3] = (short)f2bf(v.w);
    ((bfx4*)dst)[i] = o;
  }
}

// ---------------- combined mask pre-pack (ballot, 1 wave per u64) -----------
__global__ __launch_bounds__(256) void maskpack(
    const unsigned char* __restrict__ dyn,
    const unsigned char* __restrict__ causal,
    unsigned long long* __restrict__ pm) {
  const bool mbyte = (causal[32] != 0);  // dyn dtype probe (bool-as-byte?)
  const int wave = threadIdx.x >> 6, lane = threadIdx.x & 63;
  const int gid = blockIdx.x * 4 + wave;
  const int tile = gid & 31;
  const int q = (gid >> 5) & (TSEQ - 1);
  const int b = gid >> 16;
  const int g = lane >> 4, blk = (lane >> 2) & 3, r = lane & 3;
  const int k = tile * 64 + blk * 16 + g * 4 + r;
  const size_t off = ((size_t)b * TSEQ + q) * TSEQ + k;
  const bool dm = mbyte ? (dyn[off] != 0) : (((const int*)dyn)[off] != 0);
  const bool qok = (q & 3) != 3;
  const bool al =
      (((k >> 5) == (q >> 5)) || ((k <= q) && qok && (r != 3))) && !dm;
  const unsigned long long bal = __ballot(!al);
  if (lane == 0) pm[gid] = bal;
}

// ---------------- QKV NT GEMM, 128x128 tile, dbuf prefetch ------------------
__global__ __launch_bounds__(256) void gemm_qkv(
    const short* __restrict__ A, const short* __restrict__ Ball,
    const float* __restrict__ bias0, const float* __restrict__ bias1,
    const float* __restrict__ bias2,
    short* __restrict__ Oq, short* __restrict__ Ok, short* __restrict__ VT) {
  __shared__ char arena[35072];  // staging 32KB | epi tile 128x137x2B
  const int tid = threadIdx.x;
  const int w = tid >> 6, lane = tid & 63;
  const int lq = lane & 15, g = lane >> 4;
  const int wr = w >> 1, wc = w & 1;
  const int m0 = blockIdx.x * 128, n0 = blockIdx.y * 128;
  const int which = blockIdx.z;
  const short* B = Ball + (size_t)which * CDIM * CDIM;
#define ASB(bi) ((short*)(arena + (bi) * 8192))
#define BSB(bi) ((short*)(arena + 16384 + (bi) * 8192))
#define GS(bi, kt)                                                             \
  {                                                                            \
    _Pragma("unroll") for (int ph = 0; ph < 2; ++ph) {                         \
      const int c = ph * 256 + tid;                                            \
      gload16(A + (size_t)(m0 + (c >> 2)) * CDIM + (kt) * 32 + (c & 3) * 8,    \
              ASB(bi) + (ph * 256 + w * 64) * 8);                              \
      gload16(B + (size_t)(n0 + (c >> 2)) * CDIM + (kt) * 32 + (c & 3) * 8,    \
              BSB(bi) + (ph * 256 + w * 64) * 8);                              \
    }                                                                          \
  }
  GS(0, 0);
  __syncthreads();
  f32x4 acc[4][4] = {};
#pragma unroll 2
  for (int kt = 0; kt < CDIM / 32; ++kt) {
    const int bi = kt & 1;
    if (kt + 1 < CDIM / 32) GS(bi ^ 1, kt + 1);
    bfx8 af[4], bfr[4];
#pragma unroll
    for (int i = 0; i < 4; ++i)
      af[i] = *(const bfx8*)&ASB(bi)[(wr * 64 + i * 16 + lq) * 32 + g * 8];
#pragma unroll
    for (int i = 0; i < 4; ++i)
      bfr[i] = *(const bfx8*)&BSB(bi)[(wc * 64 + i * 16 + lq) * 32 + g * 8];
#pragma unroll
    for (int i = 0; i < 4; ++i)
#pragma unroll
      for (int j = 0; j < 4; ++j)
        acc[i][j] = __builtin_amdgcn_mfma_f32_16x16x32_bf16(af[i], bfr[j],
                                                            acc[i][j], 0, 0, 0);
    __syncthreads();
  }
#undef GS
  const float* bias = (which == 0) ? bias0 : (which == 1) ? bias1 : bias2;
  const float scale = (which == 0) ? 0.18033688011112042f : 1.0f;
  short* tile = (short*)arena;
  const int rs = (which == 2) ? 137 : 136;  // V path: odd stride for T-reads
#pragma unroll
  for (int i = 0; i < 4; ++i)
#pragma unroll
    for (int j = 0; j < 4; ++j) {
      const int col = wc * 64 + j * 16 + lq;
      const float bb = bias[n0 + col];
#pragma unroll
      for (int r = 0; r < 4; ++r) {
        const int row = wr * 64 + i * 16 + g * 4 + r;
        tile[row * rs + col] = (short)f2bf((acc[i][j][r] + bb) * scale);
      }
    }
  __syncthreads();
  const int b_ = m0 >> 11, t0 = m0 & (TSEQ - 1);
  if (which == 2) {
#pragma unroll
    for (int it = 0; it < 8; ++it) {
      const int id = it * 256 + tid;
      const int tseg = id & 15, d128 = id >> 4;
      const int h = (n0 >> 6) + (d128 >> 6), d = d128 & 63;
      bfx8 o;
#pragma unroll
      for (int j = 0; j < 8; ++j) o[j] = tile[(tseg * 8 + j) * 137 + d128];
      *(bfx8*)&VT[(((size_t)b_ * NHEAD + h) * DHEAD + d) * TSEQ + t0 +
                  tseg * 8] = o;
    }
  } else {
    short* O = (which == 0) ? Oq : Ok;
#pragma unroll
    for (int it = 0; it < 8; ++it) {
      const int id = it * 256 + tid;  // 2048 stores = full tile
      const int m = id >> 4, c16 = id & 15;
      const int h = (n0 >> 6) + (c16 >> 3), d0 = (c16 & 7) * 8;
      *(bfx8*)&O[(((size_t)b_ * NHEAD + h) * TSEQ + t0 + m) * DHEAD + d0] =
          *(const bfx8*)&tile[m * 136 + c16 * 8];
    }
  }
}

// ---------------- output projection NT GEMM, 64x128 tile --------------------
__global__ __launch_bounds__(256) void gemm_out(
    const short* __restrict__ A, const short* __restrict__ B,
    const float* __restrict__ bias, float* __restrict__ Of) {
  __shared__ char arena[24576];  // As 2x4KB | Bs 2x8KB
  const int tid = threadIdx.x;
  const int w = tid >> 6, lane = tid & 63;
  const int lq = lane & 15, g = lane >> 4;
  const int wr = w >> 1, wc = w & 1;
  const int m0 = blockIdx.x * 64, n0 = blockIdx.y * 128;
#define ASB(bi) ((short*)(arena + (bi) * 4096))
#define BSB(bi) ((short*)(arena + 8192 + (bi) * 8192))
#define GS(bi, kt)                                                             \
  {                                                                            \
    gload16(A + (size_t)(m0 + (tid >> 2)) * CDIM + (kt) * 32 + (tid & 3) * 8,  \
            ASB(bi) + (w * 64) * 8);                                           \
    _Pragma("unroll") for (int ph = 0; ph < 2; ++ph) {                         \
      const int c = ph * 256 + tid;                                            \
      gload16(B + (size_t)(n0 + (c >> 2)) * CDIM + (kt) * 32 + (c & 3) * 8,    \
              BSB(bi) + (ph * 256 + w * 64) * 8);                              \
    }                                                                          \
  }
  GS(0, 0);
  __syncthreads();
  f32x4 acc[2][4] = {};
#pragma unroll 2
  for (int kt = 0; kt < CDIM / 32; ++kt) {
    const int bi = kt & 1;
    if (kt + 1 < CDIM / 32) GS(bi ^ 1, kt + 1);
    bfx8 af[2], bfr[4];
#pragma unroll
    for (int i = 0; i < 2; ++i)
      af[i] = *(const bfx8*)&ASB(bi)[(wr * 32 + i * 16 + lq) * 32 + g * 8];
#pragma unroll
    for (int j = 0; j < 4; ++j)
      bfr[j] = *(const bfx8*)&BSB(bi)[(wc * 64 + j * 16 + lq) * 32 + g * 8];
#pragma unroll
    for (int i = 0; i < 2; ++i)
#pragma unroll
      for (int j = 0; j < 4; ++j)
        acc[i][j] = __builtin_amdgcn_mfma_f32_16x16x32_bf16(af[i], bfr[j],
                                                            acc[i][j], 0, 0, 0);
    __syncthreads();
  }
#undef GS
#undef ASB
#undef BSB
#pragma unroll
  for (int i = 0; i < 2; ++i)
#pragma unroll
    for (int j = 0; j < 4; ++j) {
      const int col = n0 + wc * 64 + j * 16 + lq;
      const float bb = bias[col];
#pragma unroll
      for (int r = 0; r < 4; ++r) {
        const int row = m0 + wr * 32 + i * 16 + g * 4 + r;
        Of[(size_t)row * CDIM + col] = acc[i][j][r] + bb;
      }
    }
}

// ---------------- fused flash attention v9 ----------------------------------
// v8 + (a) pm-mask loads issued BEFORE the STAGE global_load_lds (so the
// compiler's pm-use waitcnt no longer forces the staging loads to retire
// mid-phase), (b) t-loop unrolled by 2 so buf is compile-time -> all swizzled
// LDS addresses hoist out of the loop.
struct QPhase {
  bfx8 qf0, qf1;
  f32x4 acc[4];
  float m, l;
  const unsigned short* pmr;  // packed-mask base for (b,q,g)
};

__device__ __forceinline__ void attn_half(QPhase& S, const char* kbuf,
                                          const char* vbuf, short* Pw,
                                          unsigned mb, int hf, int sw, int lq,
                                          int g) {
  f32x4 st[2] = {};
  __builtin_amdgcn_s_setprio(1);
#pragma unroll
  for (int b2 = 0; b2 < 2; ++b2) {
    const int rowb = ((hf * 2 + b2) * 16 + lq) * 128;
    const bfx8 kf0 = *(const bfx8*)&kbuf[rowb + ((g * 16) ^ sw)];
    const bfx8 kf1 = *(const bfx8*)&kbuf[rowb + ((64 + g * 16) ^ sw)];
    st[b2] =
        __builtin_amdgcn_mfma_f32_16x16x32_bf16(kf0, S.qf0, st[b2], 0, 0, 0);
    st[b2] =
        __builtin_amdgcn_mfma_f32_16x16x32_bf16(kf1, S.qf1, st[b2], 0, 0, 0);
  }
  __builtin_amdgcn_s_setprio(0);
  float s8[8];
#pragma unroll
  for (int idx = 0; idx < 8; ++idx)
    s8[idx] = ((mb >> idx) & 1u) ? -3.0e38f : st[idx >> 2][idx & 3];
  const float t0 = max3f(s8[0], s8[1], s8[2]);
  const float t1 = max3f(s8[3], s8[4], s8[5]);
  const float pmax = max3f(t0, t1, fmaxf(s8[6], s8[7]));
  if (!__all(pmax - S.m <= 8.f)) {  // rare slow path
    float smax = fmaxf(pmax, __shfl_xor(pmax, 16));
    smax = fmaxf(smax, __shfl_xor(smax, 32));
    const float mnew = fmaxf(S.m, smax);
    const float fac = __builtin_amdgcn_exp2f(S.m - mnew);
    S.l *= fac;
    float fr[4];
#pragma unroll
    for (int r = 0; r < 4; ++r) fr[r] = __shfl(fac, g * 4 + r);
#pragma unroll
    for (int dc = 0; dc < 4; ++dc) {
      S.acc[dc][0] *= fr[0]; S.acc[dc][1] *= fr[1];
      S.acc[dc][2] *= fr[2]; S.acc[dc][3] *= fr[3];
    }
    S.m = mnew;
  }
  float psum = 0.f;
#pragma unroll
  for (int idx = 0; idx < 8; ++idx) {
    const float e = __builtin_amdgcn_exp2f(s8[idx] - S.m);  // masked -> +0
    s8[idx] = e;
    psum += e;
  }
  S.l += psum;  // per-lane partial
  // P round-trip (k_local = b2*16 + g*4 + r within the 32-wide half)
#pragma unroll
  for (int b2 = 0; b2 < 2; ++b2) {
    uint2 u;
    u.x = cvtpk(s8[b2 * 4 + 0], s8[b2 * 4 + 1]);
    u.y = cvtpk(s8[b2 * 4 + 2], s8[b2 * 4 + 3]);
    *(uint2*)&Pw[lq * 40 + b2 * 16 + g * 4] = u;
  }
  __builtin_amdgcn_wave_barrier();
  const bfx8 pa = *(const bfx8*)&Pw[lq * 40 + g * 8];
  __builtin_amdgcn_wave_barrier();
  __builtin_amdgcn_s_setprio(1);
#pragma unroll
  for (int dc = 0; dc < 4; ++dc) {
    const bfx8 vf = *(const bfx8*)&vbuf[(dc * 16 + lq) * 128 +
                                        ((hf * 64 + g * 16) ^ sw)];
    S.acc[dc] =
        __builtin_amdgcn_mfma_f32_16x16x32_bf16(pa, vf, S.acc[dc], 0, 0, 0);
  }
  __builtin_amdgcn_s_setprio(0);
}

__global__ __launch_bounds__(512, 4) void attn(
    const short* __restrict__ Q, const short* __restrict__ K,
    const short* __restrict__ VT, const unsigned short* __restrict__ pm,
    short* __restrict__ Y) {
  __shared__ char arena[43008];  // kv 2x16KB | P 10KB (epi: reuse)
  const int tid = threadIdx.x;
  const int w = tid >> 6, lane = tid & 63;
  const int hf = w >> 2, ws = w & 3;
  const int lq = lane & 15, g = lane >> 4;
  const int bh = blockIdx.y, b = bh >> 4, h = bh & 15;
  const int tlo = blockIdx.x, thi = 31 - tlo;  // paired q-tiles
  const short* Qb = Q + (size_t)bh * TSEQ * DHEAD;
  const short* Kb = K + (size_t)bh * TSEQ * DHEAD;
  const short* Vb = VT + (size_t)bh * DHEAD * TSEQ;

  QPhase lo, hi;
  {
    const int qlo = tlo * 64 + ws * 16 + lq;
    const int qhi = thi * 64 + ws * 16 + lq;
    lo.qf0 = *(const bfx8*)(Qb + (size_t)qlo * DHEAD + g * 8);
    lo.qf1 = *(const bfx8*)(Qb + (size_t)qlo * DHEAD + 32 + g * 8);
    hi.qf0 = *(const bfx8*)(Qb + (size_t)qhi * DHEAD + g * 8);
    hi.qf1 = *(const bfx8*)(Qb + (size_t)qhi * DHEAD + 32 + g * 8);
#pragma unroll
    for (int dc = 0; dc < 4; ++dc) { lo.acc[dc] = f32x4{}; hi.acc[dc] = f32x4{}; }
    lo.m = -1e30f; lo.l = 0.f; hi.m = -1e30f; hi.l = 0.f;
    lo.pmr = pm + ((size_t)(b * TSEQ + qlo) << 7) + g;
    hi.pmr = pm + ((size_t)(b * TSEQ + qhi) << 7) + g;
  }

  const int sl = lane >> 3, sc = lane & 7;  // staging: row sub / col16
  const int ssw = (sc ^ sl) * 8;            // pre-swizzled source col (shorts)
  const int sw = (lq & 7) << 4;             // read-side XOR (bytes)
  short* Pw = (short*)(arena + 32768 + w * 1280);  // [16][40] per wave

  // Wave-uniform LDS dest (w*1024); per-lane swizzled global source.
#define STAGE(bufn, k0s)                                                      \
  {                                                                           \
    gload16(Kb + (size_t)((k0s) + w * 8 + sl) * DHEAD + ssw,                  \
            arena + (bufn) * 16384 + w * 1024);                               \
    gload16(Vb + (size_t)(w * 8 + sl) * TSEQ + (k0s) + ssw,                   \
            arena + (bufn) * 16384 + 8192 + w * 1024);                        \
  }

  // One tile-phase. pm loads FIRST (before STAGE) so their waitcnt doesn't
  // drain the staging queue mid-phase; BUF compile-time for addr hoisting.
#define PHASE(t, BUF)                                                         \
  {                                                                           \
    const unsigned pmh = hi.pmr[(t) << 2];                                    \
    const unsigned pml = ((t) <= tlo) ? (unsigned)lo.pmr[(t) << 2] : 0u;      \
    __builtin_amdgcn_sched_barrier(0);                                        \
    if ((t) < thi) STAGE((BUF) ^ 1, ((t) + 1) * 64);                          \
    const char* kbuf_ = arena + (BUF) * 16384;                                \
    const char* vbuf_ = kbuf_ + 8192;                                         \
    attn_half(hi, kbuf_, vbuf_, Pw, (pmh >> (hf * 8)) & 0xffu, hf, sw, lq, g);\
    if ((t) <= tlo)                                                           \
      attn_half(lo, kbuf_, vbuf_, Pw, (pml >> (hf * 8)) & 0xffu, hf, sw, lq,  \
                g);                                                           \
    __syncthreads();                                                          \
  }

  STAGE(0, 0);
  __syncthreads();

  int t = 0;
  for (; t + 1 <= thi; t += 2) {
    PHASE(t, 0);
    PHASE(t + 1, 1);
  }
  if (t <= thi) PHASE(t, 0);
#undef PHASE
#undef STAGE

  // ---- merge the two k-half states (group1 -> LDS, group0 merges+stores)
  float* exA = (float*)arena;                    // 8 x 4KB acc
  float2* exM = (float2*)(arena + 32768);        // 8 x 512B (m,l)
  if (hf == 1) {
#pragma unroll
    for (int ph = 0; ph < 2; ++ph) {
      QPhase& S = ph ? hi : lo;
      float* a = exA + (ws * 2 + ph) * 1024;
#pragma unroll
      for (int dc = 0; dc < 4; ++dc)
        *(f32x4*)&a[lane * 16 + dc * 4] = S.acc[dc];
      exM[(ws * 2 + ph) * 64 + lane] = float2{S.m, S.l};
    }
  }
  __syncthreads();
  if (hf == 0) {
#pragma unroll
    for (int ph = 0; ph < 2; ++ph) {
      QPhase& S = ph ? hi : lo;
      const float* a = exA + (ws * 2 + ph) * 1024;
      const float2 mlB = exM[(ws * 2 + ph) * 64 + lane];
      const float ms = fmaxf(S.m, mlB.x);
      const float fA = __builtin_amdgcn_exp2f(S.m - ms);
      const float fB = __builtin_amdgcn_exp2f(mlB.x - ms);
      float lr = S.l * fA + mlB.y * fB;
      lr += __shfl_xor(lr, 16);
      lr += __shfl_xor(lr, 32);
      float frA[4], frB[4], li[4];
#pragma unroll
      for (int r = 0; r < 4; ++r) {
        frA[r] = __shfl(fA, g * 4 + r);
        frB[r] = __shfl(fB, g * 4 + r);
        const float lv = __shfl(lr, g * 4 + r);
        li[r] = lv > 0.f ? 1.f / lv : 0.f;
      }
      const int q0 = (ph ? thi : tlo) * 64 + ws * 16;
#pragma unroll
      for (int dc = 0; dc < 4; ++dc) {
        const f32x4 ab = *(const f32x4*)&a[lane * 16 + dc * 4];
#pragma unroll
        for (int r = 0; r < 4; ++r) {
          const int t2 = q0 + g * 4 + r;
          Y[((size_t)b * TSEQ + t2) * CDIM + h * DHEAD + dc * 16 + lq] =
              (short)f2bf((S.acc[dc][r] * frA[r] + ab[r] * frB[r]) * li[r]);
        }
      }
    }
  }
}

extern "C" void kernel_launch(void* const* d_in, const int* in_sizes, int n_in,
                              void* d_out, int out_size, void* d_ws,
                              size_t ws_size, hipStream_t stream) {
  const float* x = (const float*)d_in[0];
  const unsigned char* dyn = (const unsigned char*)d_in[1];
  const unsigned char* causal = (const unsigned char*)d_in[2];
  const float* Wq = (const float*)d_in[3];
  const float* bq = (const float*)d_in[4];
  const float* Wk = (const float*)d_in[5];
  const float* bk = (const float*)d_in[6];
  const float* Wv = (const float*)d_in[7];
  const float* bv = (const float*)d_in[8];
  const float* Wo = (const float*)d_in[9];
  const float* bo = (const float*)d_in[10];

  char* ws = (char*)d_ws;
  const size_t MB8 = 8ull * 1024 * 1024;
  short* xb = (short*)(ws + 0 * MB8);
  short* wall = (short*)(ws + 1 * MB8);  // Wq,Wk,Wv,Wo bf16 concatenated
  short* Qb = (short*)(ws + 2 * MB8);
  short* Kb = (short*)(ws + 3 * MB8);
  short* VTb = (short*)(ws + 5 * MB8);
  short* Yb = (short*)(ws + 6 * MB8);
  unsigned long long* pmask = (unsigned long long*)(ws + 7 * MB8);  // 1 MB

  convert_all<<<dim3(4096, 5), 256, 0, stream>>>(x, Wq, Wk, Wv, Wo, xb, wall);
  maskpack<<<dim3(32768), 256, 0, stream>>>(dyn, causal, pmask);
  gemm_qkv<<<dim3(32, 8, 3), 256, 0, stream>>>(xb, wall, bq, bk, bv, Qb, Kb,
                                               VTb);
  attn<<<dim3(16, 32), 512, 0, stream>>>(Qb, Kb, VTb,
                                         (const unsigned short*)pmask, Yb);
  gemm_out<<<dim3(64, 8), 256, 0, stream>>>(Yb, wall + 3 * CDIM * CDIM, bo,
                                            (float*)d_out);
}

// Round 12
// 122.344 us; speedup vs baseline: 1.3897x; 1.0371x over previous
//
#include <hip/hip_runtime.h>

#define TSEQ 2048
#define NHEAD 16
#define DHEAD 64
#define CDIM 1024
#define BATCH 2

typedef __attribute__((ext_vector_type(8))) short bfx8;
typedef __attribute__((ext_vector_type(4))) short bfx4;
typedef __attribute__((ext_vector_type(4))) float f32x4;

__device__ __forceinline__ unsigned short f2bf(float f) {
  unsigned u = __builtin_bit_cast(unsigned, f);
  u += 0x7fffu + ((u >> 16) & 1u);
  return (unsigned short)(u >> 16);
}

__device__ __forceinline__ unsigned cvtpk(float lo, float hi) {
  unsigned r;
  asm("v_cvt_pk_bf16_f32 %0, %1, %2" : "=v"(r) : "v"(lo), "v"(hi));
  return r;
}

__device__ __forceinline__ float max3f(float a, float b, float c) {
  float d;
  asm("v_max3_f32 %0, %1, %2, %3" : "=v"(d) : "v"(a), "v"(b), "v"(c));
  return d;
}

__device__ __forceinline__ void gload16(const void* g, void* l) {
  __builtin_amdgcn_global_load_lds(
      (const __attribute__((address_space(1))) unsigned*)g,
      (__attribute__((address_space(3))) unsigned*)l, 16, 0, 0);
}

// ---------------- prep: fp32->bf16 conversion + combined mask pre-pack ------
// bid < 20480: convert (y=bid>>12 selects x/Wq/Wk/Wv/Wo). bid >= 20480:
// maskpack, 1 wave per u64 word via ballot (bit l set => masked).
__global__ __launch_bounds__(256) void prep(
    const float* __restrict__ x,
    const float* __restrict__ wq, const float* __restrict__ wk,
    const float* __restrict__ wv, const float* __restrict__ wo,
    short* __restrict__ xb, short* __restrict__ wall,
    const unsigned char* __restrict__ dyn,
    const unsigned char* __restrict__ causal,
    unsigned long long* __restrict__ pm) {
  const int bid = blockIdx.x;
  if (bid < 20480) {
    const int y = bid >> 12;
    const float* src;
    short* dst;
    int n;
    if (y == 0) { src = x; dst = xb; n = (BATCH * TSEQ * CDIM) / 4; }
    else {
      src = (y == 1) ? wq : (y == 2) ? wk : (y == 3) ? wv : wo;
      dst = wall + (size_t)(y - 1) * CDIM * CDIM;
      n = (CDIM * CDIM) / 4;
    }
    const int i = (bid & 4095) * 256 + threadIdx.x;
    if (i < n) {
      const float4 v = ((const float4*)src)[i];
      bfx4 o;
      o[0] = (short)f2bf(v.x); o[1] = (short)f2bf(v.y);
      o[2] = (short)f2bf(v.z); o[3] = (short)f2bf(v.w);
      ((bfx4*)dst)[i] = o;
    }
  } else {
    const bool mbyte = (causal[32] != 0);  // dyn dtype probe
    const int wave = threadIdx.x >> 6, lane = threadIdx.x & 63;
    const int gid = (bid - 20480) * 4 + wave;
    const int tile = gid & 31;
    const int q = (gid >> 5) & (TSEQ - 1);
    const int b = gid >> 16;
    const int g = lane >> 4, blk = (lane >> 2) & 3, r = lane & 3;
    const int k = tile * 64 + blk * 16 + g * 4 + r;
    const size_t off = ((size_t)b * TSEQ + q) * TSEQ + k;
    const bool dm = mbyte ? (dyn[off] != 0) : (((const int*)dyn)[off] != 0);
    const bool qok = (q & 3) != 3;
    const bool al =
        (((k >> 5) == (q >> 5)) || ((k <= q) && qok && (r != 3))) && !dm;
    const unsigned long long bal = __ballot(!al);
    if (lane == 0) pm[gid] = bal;
  }
}

// ---------------- QKV NT GEMM, 128x128 tile, dbuf prefetch ------------------
// XCD-chunked 1-D grid (768 = 8 xcd x 96): xcd gets 8 m-tiles x 12 (n,z)
// panels -> per-XCD working set A 2MB + B 3MB fits the 4MB XCD L2.
__global__ __launch_bounds__(256) void gemm_qkv(
    const short* __restrict__ A, const short* __restrict__ Ball,
    const float* __restrict__ bias0, const float* __restrict__ bias1,
    const float* __restrict__ bias2,
    short* __restrict__ Oq, short* __restrict__ Ok, short* __restrict__ VT) {
  __shared__ char arena[35072];  // staging 32KB | epi tile 128x137x2B
  const int bid = blockIdx.x;
  const int xcd = bid & 7, local = bid >> 3;      // local in [0,96)
  const int m_idx = (xcd >> 1) * 8 + (local & 7); // [0,32)
  const int nz = (xcd & 1) * 12 + (local >> 3);   // [0,24)
  const int which = nz >> 3, n_idx = nz & 7;
  const int tid = threadIdx.x;
  const int w = tid >> 6, lane = tid & 63;
  const int lq = lane & 15, g = lane >> 4;
  const int wr = w >> 1, wc = w & 1;
  const int m0 = m_idx * 128, n0 = n_idx * 128;
  const short* B = Ball + (size_t)which * CDIM * CDIM;
#define ASB(bi) ((short*)(arena + (bi) * 8192))
#define BSB(bi) ((short*)(arena + 16384 + (bi) * 8192))
#define GS(bi, kt)                                                             \
  {                                                                            \
    _Pragma("unroll") for (int ph = 0; ph < 2; ++ph) {                         \
      const int c = ph * 256 + tid;                                            \
      gload16(A + (size_t)(m0 + (c >> 2)) * CDIM + (kt) * 32 + (c & 3) * 8,    \
              ASB(bi) + (ph * 256 + w * 64) * 8);                              \
      gload16(B + (size_t)(n0 + (c >> 2)) * CDIM + (kt) * 32 + (c & 3) * 8,    \
              BSB(bi) + (ph * 256 + w * 64) * 8);                              \
    }                                                                          \
  }
  GS(0, 0);
  __syncthreads();
  f32x4 acc[4][4] = {};
#pragma unroll 2
  for (int kt = 0; kt < CDIM / 32; ++kt) {
    const int bi = kt & 1;
    if (kt + 1 < CDIM / 32) GS(bi ^ 1, kt + 1);
    bfx8 af[4], bfr[4];
#pragma unroll
    for (int i = 0; i < 4; ++i)
      af[i] = *(const bfx8*)&ASB(bi)[(wr * 64 + i * 16 + lq) * 32 + g * 8];
#pragma unroll
    for (int i = 0; i < 4; ++i)
      bfr[i] = *(const bfx8*)&BSB(bi)[(wc * 64 + i * 16 + lq) * 32 + g * 8];
#pragma unroll
    for (int i = 0; i < 4; ++i)
#pragma unroll
      for (int j = 0; j < 4; ++j)
        acc[i][j] = __builtin_amdgcn_mfma_f32_16x16x32_bf16(af[i], bfr[j],
                                                            acc[i][j], 0, 0, 0);
    __syncthreads();
  }
#undef GS
  const float* bias = (which == 0) ? bias0 : (which == 1) ? bias1 : bias2;
  const float scale = (which == 0) ? 0.18033688011112042f : 1.0f;
  short* tile = (short*)arena;
  const int rs = (which == 2) ? 137 : 136;  // V path: odd stride for T-reads
#pragma unroll
  for (int i = 0; i < 4; ++i)
#pragma unroll
    for (int j = 0; j < 4; ++j) {
      const int col = wc * 64 + j * 16 + lq;
      const float bb = bias[n0 + col];
#pragma unroll
      for (int r = 0; r < 4; ++r) {
        const int row = wr * 64 + i * 16 + g * 4 + r;
        tile[row * rs + col] = (short)f2bf((acc[i][j][r] + bb) * scale);
      }
    }
  __syncthreads();
  const int b_ = m0 >> 11, t0 = m0 & (TSEQ - 1);
  if (which == 2) {
#pragma unroll
    for (int it = 0; it < 8; ++it) {
      const int id = it * 256 + tid;
      const int tseg = id & 15, d128 = id >> 4;
      const int h = (n0 >> 6) + (d128 >> 6), d = d128 & 63;
      bfx8 o;
#pragma unroll
      for (int j = 0; j < 8; ++j) o[j] = tile[(tseg * 8 + j) * 137 + d128];
      *(bfx8*)&VT[(((size_t)b_ * NHEAD + h) * DHEAD + d) * TSEQ + t0 +
                  tseg * 8] = o;
    }
  } else {
    short* O = (which == 0) ? Oq : Ok;
#pragma unroll
    for (int it = 0; it < 8; ++it) {
      const int id = it * 256 + tid;  // 2048 stores = full tile
      const int m = id >> 4, c16 = id & 15;
      const int h = (n0 >> 6) + (c16 >> 3), d0 = (c16 & 7) * 8;
      *(bfx8*)&O[(((size_t)b_ * NHEAD + h) * TSEQ + t0 + m) * DHEAD + d0] =
          *(const bfx8*)&tile[m * 136 + c16 * 8];
    }
  }
}

// ---------------- output projection NT GEMM, 64x128 tile --------------------
// XCD-chunked 1-D grid (512 = 8 x 64): xcd gets 16 m x 4 n (A 2MB + B 1MB).
__global__ __launch_bounds__(256) void gemm_out(
    const short* __restrict__ A, const short* __restrict__ B,
    const float* __restrict__ bias, float* __restrict__ Of) {
  __shared__ char arena[24576];  // As 2x4KB | Bs 2x8KB
  const int bid = blockIdx.x;
  const int xcd = bid & 7, local = bid >> 3;        // local in [0,64)
  const int m_idx = (xcd >> 1) * 16 + (local & 15); // [0,64)
  const int n_idx = (xcd & 1) * 4 + (local >> 4);   // [0,8)
  const int tid = threadIdx.x;
  const int w = tid >> 6, lane = tid & 63;
  const int lq = lane & 15, g = lane >> 4;
  const int wr = w >> 1, wc = w & 1;
  const int m0 = m_idx * 64, n0 = n_idx * 128;
#define ASB(bi) ((short*)(arena + (bi) * 4096))
#define BSB(bi) ((short*)(arena + 8192 + (bi) * 8192))
#define GS(bi, kt)                                                             \
  {                                                                            \
    gload16(A + (size_t)(m0 + (tid >> 2)) * CDIM + (kt) * 32 + (tid & 3) * 8,  \
            ASB(bi) + (w * 64) * 8);                                           \
    _Pragma("unroll") for (int ph = 0; ph < 2; ++ph) {                         \
      const int c = ph * 256 + tid;                                            \
      gload16(B + (size_t)(n0 + (c >> 2)) * CDIM + (kt) * 32 + (c & 3) * 8,    \
              BSB(bi) + (ph * 256 + w * 64) * 8);                              \
    }                                                                          \
  }
  GS(0, 0);
  __syncthreads();
  f32x4 acc[2][4] = {};
#pragma unroll 2
  for (int kt = 0; kt < CDIM / 32; ++kt) {
    const int bi = kt & 1;
    if (kt + 1 < CDIM / 32) GS(bi ^ 1, kt + 1);
    bfx8 af[2], bfr[4];
#pragma unroll
    for (int i = 0; i < 2; ++i)
      af[i] = *(const bfx8*)&ASB(bi)[(wr * 32 + i * 16 + lq) * 32 + g * 8];
#pragma unroll
    for (int j = 0; j < 4; ++j)
      bfr[j] = *(const bfx8*)&BSB(bi)[(wc * 64 + j * 16 + lq) * 32 + g * 8];
#pragma unroll
    for (int i = 0; i < 2; ++i)
#pragma unroll
      for (int j = 0; j < 4; ++j)
        acc[i][j] = __builtin_amdgcn_mfma_f32_16x16x32_bf16(af[i], bfr[j],
                                                            acc[i][j], 0, 0, 0);
    __syncthreads();
  }
#undef GS
#undef ASB
#undef BSB
#pragma unroll
  for (int i = 0; i < 2; ++i)
#pragma unroll
    for (int j = 0; j < 4; ++j) {
      const int col = n0 + wc * 64 + j * 16 + lq;
      const float bb = bias[col];
#pragma unroll
      for (int r = 0; r < 4; ++r) {
        const int row = m0 + wr * 32 + i * 16 + g * 4 + r;
        Of[(size_t)row * CDIM + col] = acc[i][j][r] + bb;
      }
    }
}

// ---------------- fused flash attention v10 ---------------------------------
// v9 + XCD-chunked 1-D grid (512 = 8 xcd x 64): xcd gets 4 consecutive bh x
// all 16 q-pairs -> per-XCD K/V = 2MB, L2-resident; phase-end vmcnt(0) drains
// become L2-latency instead of HBM.
struct QPhase {
  bfx8 qf0, qf1;
  f32x4 acc[4];
  float m, l;
  const unsigned short* pmr;  // packed-mask base for (b,q,g)
};

__device__ __forceinline__ void attn_half(QPhase& S, const char* kbuf,
                                          const char* vbuf, short* Pw,
                                          unsigned mb, int hf, int sw, int lq,
                                          int g) {
  f32x4 st[2] = {};
  __builtin_amdgcn_s_setprio(1);
#pragma unroll
  for (int b2 = 0; b2 < 2; ++b2) {
    const int rowb = ((hf * 2 + b2) * 16 + lq) * 128;
    const bfx8 kf0 = *(const bfx8*)&kbuf[rowb + ((g * 16) ^ sw)];
    const bfx8 kf1 = *(const bfx8*)&kbuf[rowb + ((64 + g * 16) ^ sw)];
    st[b2] =
        __builtin_amdgcn_mfma_f32_16x16x32_bf16(kf0, S.qf0, st[b2], 0, 0, 0);
    st[b2] =
        __builtin_amdgcn_mfma_f32_16x16x32_bf16(kf1, S.qf1, st[b2], 0, 0, 0);
  }
  __builtin_amdgcn_s_setprio(0);
  float s8[8];
#pragma unroll
  for (int idx = 0; idx < 8; ++idx)
    s8[idx] = ((mb >> idx) & 1u) ? -3.0e38f : st[idx >> 2][idx & 3];
  const float t0 = max3f(s8[0], s8[1], s8[2]);
  const float t1 = max3f(s8[3], s8[4], s8[5]);
  const float pmax = max3f(t0, t1, fmaxf(s8[6], s8[7]));
  if (!__all(pmax - S.m <= 8.f)) {  // rare slow path
    float smax = fmaxf(pmax, __shfl_xor(pmax, 16));
    smax = fmaxf(smax, __shfl_xor(smax, 32));
    const float mnew = fmaxf(S.m, smax);
    const float fac = __builtin_amdgcn_exp2f(S.m - mnew);
    S.l *= fac;
    float fr[4];
#pragma unroll
    for (int r = 0; r < 4; ++r) fr[r] = __shfl(fac, g * 4 + r);
#pragma unroll
    for (int dc = 0; dc < 4; ++dc) {
      S.acc[dc][0] *= fr[0]; S.acc[dc][1] *= fr[1];
      S.acc[dc][2] *= fr[2]; S.acc[dc][3] *= fr[3];
    }
    S.m = mnew;
  }
  float psum = 0.f;
#pragma unroll
  for (int idx = 0; idx < 8; ++idx) {
    const float e = __builtin_amdgcn_exp2f(s8[idx] - S.m);  // masked -> +0
    s8[idx] = e;
    psum += e;
  }
  S.l += psum;  // per-lane partial
#pragma unroll
  for (int b2 = 0; b2 < 2; ++b2) {
    uint2 u;
    u.x = cvtpk(s8[b2 * 4 + 0], s8[b2 * 4 + 1]);
    u.y = cvtpk(s8[b2 * 4 + 2], s8[b2 * 4 + 3]);
    *(uint2*)&Pw[lq * 40 + b2 * 16 + g * 4] = u;
  }
  __builtin_amdgcn_wave_barrier();
  const bfx8 pa = *(const bfx8*)&Pw[lq * 40 + g * 8];
  __builtin_amdgcn_wave_barrier();
  __builtin_amdgcn_s_setprio(1);
#pragma unroll
  for (int dc = 0; dc < 4; ++dc) {
    const bfx8 vf = *(const bfx8*)&vbuf[(dc * 16 + lq) * 128 +
                                        ((hf * 64 + g * 16) ^ sw)];
    S.acc[dc] =
        __builtin_amdgcn_mfma_f32_16x16x32_bf16(pa, vf, S.acc[dc], 0, 0, 0);
  }
  __builtin_amdgcn_s_setprio(0);
}

__global__ __launch_bounds__(512, 4) void attn(
    const short* __restrict__ Q, const short* __restrict__ K,
    const short* __restrict__ VT, const unsigned short* __restrict__ pm,
    short* __restrict__ Y) {
  __shared__ char arena[43008];  // kv 2x16KB | P 10KB (epi: reuse)
  const int bid = blockIdx.x;
  const int local = bid >> 3;                 // [0,64)
  const int bh = (bid & 7) * 4 + (local >> 4);  // 4 bh per XCD
  const int tlo = local & 15, thi = 31 - tlo;   // paired q-tiles
  const int tid = threadIdx.x;
  const int w = tid >> 6, lane = tid & 63;
  const int hf = w >> 2, ws = w & 3;
  const int lq = lane & 15, g = lane >> 4;
  const int b = bh >> 4, h = bh & 15;
  const short* Qb = Q + (size_t)bh * TSEQ * DHEAD;
  const short* Kb = K + (size_t)bh * TSEQ * DHEAD;
  const short* Vb = VT + (size_t)bh * DHEAD * TSEQ;

  QPhase lo, hi;
  {
    const int qlo = tlo * 64 + ws * 16 + lq;
    const int qhi = thi * 64 + ws * 16 + lq;
    lo.qf0 = *(const bfx8*)(Qb + (size_t)qlo * DHEAD + g * 8);
    lo.qf1 = *(const bfx8*)(Qb + (size_t)qlo * DHEAD + 32 + g * 8);
    hi.qf0 = *(const bfx8*)(Qb + (size_t)qhi * DHEAD + g * 8);
    hi.qf1 = *(const bfx8*)(Qb + (size_t)qhi * DHEAD + 32 + g * 8);
#pragma unroll
    for (int dc = 0; dc < 4; ++dc) { lo.acc[dc] = f32x4{}; hi.acc[dc] = f32x4{}; }
    lo.m = -1e30f; lo.l = 0.f; hi.m = -1e30f; hi.l = 0.f;
    lo.pmr = pm + ((size_t)(b * TSEQ + qlo) << 7) + g;
    hi.pmr = pm + ((size_t)(b * TSEQ + qhi) << 7) + g;
  }

  const int sl = lane >> 3, sc = lane & 7;  // staging: row sub / col16
  const int ssw = (sc ^ sl) * 8;            // pre-swizzled source col (shorts)
  const int sw = (lq & 7) << 4;             // read-side XOR (bytes)
  short* Pw = (short*)(arena + 32768 + w * 1280);  // [16][40] per wave

#define STAGE(bufn, k0s)                                                      \
  {                                                                           \
    gload16(Kb + (size_t)((k0s) + w * 8 + sl) * DHEAD + ssw,                  \
            arena + (bufn) * 16384 + w * 1024);                               \
    gload16(Vb + (size_t)(w * 8 + sl) * TSEQ + (k0s) + ssw,                   \
            arena + (bufn) * 16384 + 8192 + w * 1024);                        \
  }

#define PHASE(t, BUF)                                                         \
  {                                                                           \
    const unsigned pmh = hi.pmr[(t) << 2];                                    \
    const unsigned pml = ((t) <= tlo) ? (unsigned)lo.pmr[(t) << 2] : 0u;      \
    __builtin_amdgcn_sched_barrier(0);                                        \
    if ((t) < thi) STAGE((BUF) ^ 1, ((t) + 1) * 64);                          \
    const char* kbuf_ = arena + (BUF) * 16384;                                \
    const char* vbuf_ = kbuf_ + 8192;                                         \
    attn_half(hi, kbuf_, vbuf_, Pw, (pmh >> (hf * 8)) & 0xffu, hf, sw, lq, g);\
    if ((t) <= tlo)                                                           \
      attn_half(lo, kbuf_, vbuf_, Pw, (pml >> (hf * 8)) & 0xffu, hf, sw, lq,  \
                g);                                                           \
    __syncthreads();                                                          \
  }

  STAGE(0, 0);
  __syncthreads();

  int t = 0;
  for (; t + 1 <= thi; t += 2) {
    PHASE(t, 0);
    PHASE(t + 1, 1);
  }
  if (t <= thi) PHASE(t, 0);
#undef PHASE
#undef STAGE

  // ---- merge the two k-half states (group1 -> LDS, group0 merges+stores)
  float* exA = (float*)arena;                    // 8 x 4KB acc
  float2* exM = (float2*)(arena + 32768);        // 8 x 512B (m,l)
  if (hf == 1) {
#pragma unroll
    for (int ph = 0; ph < 2; ++ph) {
      QPhase& S = ph ? hi : lo;
      float* a = exA + (ws * 2 + ph) * 1024;
#pragma unroll
      for (int dc = 0; dc < 4; ++dc)
        *(f32x4*)&a[lane * 16 + dc * 4] = S.acc[dc];
      exM[(ws * 2 + ph) * 64 + lane] = float2{S.m, S.l};
    }
  }
  __syncthreads();
  if (hf == 0) {
#pragma unroll
    for (int ph = 0; ph < 2; ++ph) {
      QPhase& S = ph ? hi : lo;
      const float* a = exA + (ws * 2 + ph) * 1024;
      const float2 mlB = exM[(ws * 2 + ph) * 64 + lane];
      const float ms = fmaxf(S.m, mlB.x);
      const float fA = __builtin_amdgcn_exp2f(S.m - ms);
      const float fB = __builtin_amdgcn_exp2f(mlB.x - ms);
      float lr = S.l * fA + mlB.y * fB;
      lr += __shfl_xor(lr, 16);
      lr += __shfl_xor(lr, 32);
      float frA[4], frB[4], li[4];
#pragma unroll
      for (int r = 0; r < 4; ++r) {
        frA[r] = __shfl(fA, g * 4 + r);
        frB[r] = __shfl(fB, g * 4 + r);
        const float lv = __shfl(lr, g * 4 + r);
        li[r] = lv > 0.f ? 1.f / lv : 0.f;
      }
      const int q0 = (ph ? thi : tlo) * 64 + ws * 16;
#pragma unroll
      for (int dc = 0; dc < 4; ++dc) {
        const f32x4 ab = *(const f32x4*)&a[lane * 16 + dc * 4];
#pragma unroll
        for (int r = 0; r < 4; ++r) {
          const int t2 = q0 + g * 4 + r;
          Y[((size_t)b * TSEQ + t2) * CDIM + h * DHEAD + dc * 16 + lq] =
              (short)f2bf((S.acc[dc][r] * frA[r] + ab[r] * frB[r]) * li[r]);
        }
      }
    }
  }
}

extern "C" void kernel_launch(void* const* d_in, const int* in_sizes, int n_in,
                              void* d_out, int out_size, void* d_ws,
                              size_t ws_size, hipStream_t stream) {
  const float* x = (const float*)d_in[0];
  const unsigned char* dyn = (const unsigned char*)d_in[1];
  const unsigned char* causal = (const unsigned char*)d_in[2];
  const float* Wq = (const float*)d_in[3];
  const float* bq = (const float*)d_in[4];
  const float* Wk = (const float*)d_in[5];
  const float* bk = (const float*)d_in[6];
  const float* Wv = (const float*)d_in[7];
  const float* bv = (const float*)d_in[8];
  const float* Wo = (const float*)d_in[9];
  const float* bo = (const float*)d_in[10];

  char* ws = (char*)d_ws;
  const size_t MB8 = 8ull * 1024 * 1024;
  short* xb = (short*)(ws + 0 * MB8);
  short* wall = (short*)(ws + 1 * MB8);  // Wq,Wk,Wv,Wo bf16 concatenated
  short* Qb = (short*)(ws + 2 * MB8);
  short* Kb = (short*)(ws + 3 * MB8);
  short* VTb = (short*)(ws + 5 * MB8);
  short* Yb = (short*)(ws + 6 * MB8);
  unsigned long long* pmask = (unsigned long long*)(ws + 7 * MB8);  // 1 MB

  prep<<<dim3(53248), 256, 0, stream>>>(x, Wq, Wk, Wv, Wo, xb, wall, dyn,
                                        causal, pmask);
  gemm_qkv<<<dim3(768), 256, 0, stream>>>(xb, wall, bq, bk, bv, Qb, Kb, VTb);
  attn<<<dim3(512), 512, 0, stream>>>(Qb, Kb, VTb,
                                      (const unsigned short*)pmask, Yb);
  gemm_out<<<dim3(512), 256, 0, stream>>>(Yb, wall + 3 * CDIM * CDIM, bo,
                                          (float*)d_out);
}